// Round 9
// baseline (391.190 us; speedup 1.0000x reference)
//
#include <hip/hip_runtime.h>
#include <stdint.h>

typedef unsigned short u16;
typedef unsigned int   u32;
typedef __bf16 bf16x8 __attribute__((ext_vector_type(8)));
typedef float  f32x4  __attribute__((ext_vector_type(4)));
typedef u32    u32x4  __attribute__((ext_vector_type(4)));
typedef u16    u16x4  __attribute__((ext_vector_type(4)));

#define SQL  1024
#define SKV  2048
#define DQ   512
#define NH   8
#define DH   64
#define NEGC (-1e9f)
#define SCALEC 0.125f

// ---- d_ws layout (u16 elements), total 15,597,568 u16 = 31.2 MB ----
#define OFF_QB  0ull
#define OFF_QP  2097152ull
#define OFF_KP  4194304ull
#define OFF_VPT 8388608ull
#define OFF_AP  12582912ull
#define OFF_BQ  14680064ull
#define OFF_BK  14942208ull
#define OFF_BV  15204352ull
#define OFF_BO  15466496ull
#define WS_NEED_BYTES (15597568ull * 2ull)

__device__ __forceinline__ u16 f2bf(float f) {
  u32 u = __float_as_uint(f);
  u32 r = u + 0x7fffu + ((u >> 16) & 1u);   // RNE
  return (u16)(r >> 16);
}
__device__ __forceinline__ float bf2f(u16 h) {
  return __uint_as_float(((u32)h) << 16);
}
__device__ __forceinline__ bf16x8 ld16(const u16* p) {
  return __builtin_bit_cast(bf16x8, *(const u32x4*)p);
}
__device__ __forceinline__ f32x4 MFMA(bf16x8 a, bf16x8 b, f32x4 c) {
  return __builtin_amdgcn_mfma_f32_16x16x32_bf16(a, b, c, 0, 0, 0);
}
__device__ __forceinline__ void cvt8(const float* src, u16* dst, int t) {
  f32x4 a = ((const f32x4*)src)[2 * t], b = ((const f32x4*)src)[2 * t + 1];
  u32x4 o;
  o[0] = (u32)f2bf(a[0]) | ((u32)f2bf(a[1]) << 16);
  o[1] = (u32)f2bf(a[2]) | ((u32)f2bf(a[3]) << 16);
  o[2] = (u32)f2bf(b[0]) | ((u32)f2bf(b[1]) << 16);
  o[3] = (u32)f2bf(b[2]) | ((u32)f2bf(b[3]) << 16);
  *(u32x4*)(dst + 8 * t) = o;
}

// ---------------- f32 code marker ----------------
__global__ void k_markf(float* outp, float val) {
  if (threadIdx.x == 0 && blockIdx.x == 0) outp[0] = val;
}

// ---------------- f32 -> bf16 conversions ----------------
__global__ __launch_bounds__(256) void k_conv_x(
    const float* __restrict__ Q, const float* __restrict__ K, const float* __restrict__ V,
    u16* __restrict__ Qb, u16* __restrict__ Kb, u16* __restrict__ Vb)
{
  int t = blockIdx.x * 256 + threadIdx.x;
  if (t < 262144)       cvt8(Q, Qb, t);
  else if (t < 786432)  cvt8(K, Kb, t - 262144);
  else                  cvt8(V, Vb, t - 786432);
}

__global__ __launch_bounds__(256) void k_conv_w(
    const float* __restrict__ Wq, const float* __restrict__ Wk,
    const float* __restrict__ Wv, const float* __restrict__ Wo,
    u16* __restrict__ BQ, u16* __restrict__ BK, u16* __restrict__ BV, u16* __restrict__ BO)
{
  int t = blockIdx.x * 256 + threadIdx.x;
  if (t < 32768)        cvt8(Wq, BQ, t);
  else if (t < 65536)   cvt8(Wk, BK, t - 32768);
  else if (t < 98304)   cvt8(Wv, BV, t - 65536);
  else                  cvt8(Wo, BO, t - 98304);
}

// ---------------- GEMM: out[m][n] = sum_k A[m][k]*B2[n][k] + bias[n], K=512 ----------------
template <typename OUT_T>
__global__ __launch_bounds__(256) void k_gemm(
    const u16* __restrict__ A, int lda,
    const u16* __restrict__ B2, int ldb,
    const float* __restrict__ bias,
    OUT_T* __restrict__ out, int ldo)
{
  __shared__ u16 As[128 * 72], Bs[128 * 72];
  const int tid = threadIdx.x;
  const int wid = tid >> 6, ln = tid & 63;
  const int l15 = ln & 15, lh = ln >> 4;
  const int m0 = blockIdx.x * 128, n0 = blockIdx.y * 128;
  const int wm = (wid & 1) * 64, wn = (wid >> 1) * 64;

  f32x4 acc[4][4];
#pragma unroll
  for (int mi = 0; mi < 4; ++mi)
#pragma unroll
    for (int ni = 0; ni < 4; ++ni) acc[mi][ni] = (f32x4){0.f, 0.f, 0.f, 0.f};

  for (int k0 = 0; k0 < 512; k0 += 64) {
#pragma unroll
    for (int s5 = 0; s5 < 4; ++s5) {
      int ci = s5 * 256 + tid;
      int row = ci >> 3, kc = ci & 7;
      *(u32x4*)(As + row * 72 + kc * 8) =
          *(const u32x4*)(A + (size_t)(m0 + row) * lda + k0 + kc * 8);
      *(u32x4*)(Bs + row * 72 + kc * 8) =
          *(const u32x4*)(B2 + (size_t)(n0 + row) * ldb + k0 + kc * 8);
    }
    __syncthreads();
    bf16x8 af[4][2], bfr[4][2];
#pragma unroll
    for (int mi = 0; mi < 4; ++mi) {
      int r = wm + mi * 16 + l15;
#pragma unroll
      for (int ks = 0; ks < 2; ++ks)
        af[mi][ks] = ld16(As + r * 72 + (ks * 4 + lh) * 8);
    }
#pragma unroll
    for (int ni = 0; ni < 4; ++ni) {
      int r = wn + ni * 16 + l15;
#pragma unroll
      for (int ks = 0; ks < 2; ++ks)
        bfr[ni][ks] = ld16(Bs + r * 72 + (ks * 4 + lh) * 8);
    }
#pragma unroll
    for (int mi = 0; mi < 4; ++mi)
#pragma unroll
      for (int ni = 0; ni < 4; ++ni) {
        acc[mi][ni] = MFMA(af[mi][0], bfr[ni][0], acc[mi][ni]);
        acc[mi][ni] = MFMA(af[mi][1], bfr[ni][1], acc[mi][ni]);
      }
    __syncthreads();
  }
  float bv[4];
#pragma unroll
  for (int ni = 0; ni < 4; ++ni) bv[ni] = bias[n0 + wn + ni * 16 + l15];
#pragma unroll
  for (int mi = 0; mi < 4; ++mi)
#pragma unroll
    for (int ni = 0; ni < 4; ++ni)
#pragma unroll
      for (int j = 0; j < 4; ++j) {
        float v = acc[mi][ni][j] + bv[ni];
        size_t idx = (size_t)(m0 + wm + mi * 16 + lh * 4 + j) * ldo + n0 + wn + ni * 16 + l15;
        if constexpr (sizeof(OUT_T) == 4) out[idx] = v;
        else                              out[idx] = f2bf(v);
      }
}

// ---------------- VP [8192][512] -> VpT [b][h][64][2048] ----------------
__global__ __launch_bounds__(256) void k_transpose(const u16* __restrict__ Vp, u16* __restrict__ VpT)
{
  __shared__ u16 T[64 * 72];
  const int bh = blockIdx.x, kt = blockIdx.y;
  const int b = bh >> 3, h = bh & 7;
  const int tid = threadIdx.x;
#pragma unroll
  for (int s = 0; s < 2; ++s) {
    int ci = s * 256 + tid;
    int row = ci >> 3, dc = ci & 7;
    *(u32x4*)(T + row * 72 + dc * 8) =
        *(const u32x4*)(Vp + (size_t)(b * 2048 + kt * 64 + row) * 512 + h * 64 + dc * 8);
  }
  __syncthreads();
#pragma unroll
  for (int s = 0; s < 2; ++s) {
    int ci = s * 256 + tid;
    int d = ci >> 3, kc = ci & 7;
    u32x4 v;
#pragma unroll
    for (int i = 0; i < 4; ++i) {
      u32 lo = T[(kc * 8 + 2 * i)     * 72 + d];
      u32 hi = T[(kc * 8 + 2 * i + 1) * 72 + d];
      v[i] = lo | (hi << 16);
    }
    *(u32x4*)(VpT + ((size_t)(b * 8 + h) * 64 + d) * 2048 + kt * 64 + kc * 8) = v;
  }
}

// ---------------- fused attention, transposed-S + vectorized masks, no-max softmax ----------------
// grid (rt=64, b=4, hg=2); block 512 = 8 waves.
// wave w: head = hg*4 + (w&3), kvhalf = w>>2 -> kv [kvhalf*1024, +1024)
// S^T trick: MFMA(K,Q) -> lane holds q-row (l15) x 4 consecutive k-cols (lh*4+j)
__global__ __launch_bounds__(512, 4) void k_attn(
    const u16* __restrict__ Qp, const u16* __restrict__ Kp, const u16* __restrict__ VpT,
    const float* __restrict__ aff, const int* __restrict__ qbm, const int* __restrict__ kvm,
    float* __restrict__ wout, u16* __restrict__ AP)
{
  __shared__ u16 Plds[8 * 16 * 72];
  __shared__ float Ls[8][16];
  __shared__ float AccX[4][64][16];
  const int tid = threadIdx.x;
  const int w = tid >> 6, ln = tid & 63;
  const int l15 = ln & 15, lh = ln >> 4;
  const int b = blockIdx.y, rt = blockIdx.x, hg = blockIdx.z;
  const int h = hg * 4 + (w & 3);
  const int kvhalf = w >> 2;
  const int kv0 = kvhalf * 1024;
  const int r0 = rt * 16;
  const int bh = b * NH + h;
  u16* Pl = Plds + w * 16 * 72;

  bf16x8 qa0, qa1;
  {
    const u16* qp = Qp + (size_t)(b * SQL + r0 + l15) * DQ + h * DH + lh * 8;
    qa0 = ld16(qp); qa1 = ld16(qp + 32);
  }

  const int    myrow   = r0 + l15;                    // this lane's q-row
  const float* affRow  = aff + ((size_t)b * SQL + myrow) * SKV;
  const int*   qbRow   = qbm + ((size_t)b * SQL + myrow) * SKV;
  const int*   kvb     = kvm + (size_t)b * SKV;
  float*       woutRow = wout + ((size_t)bh * SQL + myrow) * SKV;

  // s[ni][j] = S[q-row = myrow][k-col = kb + ni*16 + lh*4 + j]
  auto compute_s = [&](int kb, f32x4* s) {
#pragma unroll
    for (int ni = 0; ni < 4; ++ni) {
      const u16* kp = Kp + (size_t)(b * SKV + kb + ni * 16 + l15) * DQ + h * DH + lh * 8;
      bf16x8 k0 = ld16(kp), k1 = ld16(kp + 32);
      f32x4 z = (f32x4){0.f, 0.f, 0.f, 0.f};
      z = MFMA(k0, qa0, z);   // swapped: A=K rows (k-cols), B=Q rows -> D = S^T
      z = MFMA(k1, qa1, z);
      s[ni] = z;
    }
#pragma unroll
    for (int ni = 0; ni < 4; ++ni) {
      const int c4 = kb + ni * 16 + lh * 4;
      f32x4 a  = *(const f32x4*)(affRow + c4);
      u32x4 qm = *(const u32x4*)(qbRow + c4);
      u32x4 km = *(const u32x4*)(kvb + c4);
#pragma unroll
      for (int j = 0; j < 4; ++j) {
        float v = s[ni][j] * SCALEC;
        v = km[j] ? NEGC : v;   // kv mask BEFORE aff (ref order)
        v = v * a[j];
        v = qm[j] ? NEGC : v;
        s[ni][j] = v;
      }
    }
  };

  // ---- pass A: sum of exp(s) (scores are bounded; masked -> exp(-1e9)=0) ----
  float sum = 0.f;
  for (int t = 0; t < 16; ++t) {
    f32x4 s[4];
    compute_s(kv0 + t * 64, s);
#pragma unroll
    for (int ni = 0; ni < 4; ++ni)
#pragma unroll
      for (int j = 0; j < 4; ++j) sum += __expf(s[ni][j]);
  }
  // reduce across the 4 lanes (lh groups) sharing this q-row
  sum += __shfl_xor(sum, 16);
  sum += __shfl_xor(sum, 32);
  // cross-wave (kv-half) combine via LDS
  if (ln < 16) Ls[w][ln] = sum;
  __syncthreads();
  const float rl = 1.0f / (sum + Ls[w ^ 4][l15]);

  f32x4 acc[4];
#pragma unroll
  for (int nd = 0; nd < 4; ++nd) acc[nd] = (f32x4){0.f, 0.f, 0.f, 0.f};

  // ---- pass B: recompute s, write f32 weights (vectorized), partial PV ----
  for (int t = 0; t < 16; ++t) {
    const int kb = kv0 + t * 64;
    f32x4 s[4];
    compute_s(kb, s);
#pragma unroll
    for (int ni = 0; ni < 4; ++ni) {
      f32x4 wv;
      u16x4 pb;
#pragma unroll
      for (int j = 0; j < 4; ++j) {
        wv[j] = __expf(s[ni][j]) * rl;
        pb[j] = f2bf(wv[j]);
      }
      *(f32x4*)(woutRow + kb + ni * 16 + lh * 4) = wv;
      *(u16x4*)(Pl + l15 * 72 + ni * 16 + lh * 4) = pb;
    }
    asm volatile("s_waitcnt lgkmcnt(0)" ::: "memory");
    bf16x8 pa0 = ld16(Pl + l15 * 72 + lh * 8);
    bf16x8 pa1 = ld16(Pl + l15 * 72 + 32 + lh * 8);
#pragma unroll
    for (int nd = 0; nd < 4; ++nd) {
      const u16* vp = VpT + (size_t)(bh * DH + nd * 16 + l15) * SKV + kb + lh * 8;
      bf16x8 v0 = ld16(vp);
      bf16x8 v1 = ld16(vp + 32);
      acc[nd] = MFMA(pa0, v0, acc[nd]);
      acc[nd] = MFMA(pa1, v1, acc[nd]);
    }
  }

  // ---- combine partial PV across kv-halves, write AP ----
  if (w >= 4) {
#pragma unroll
    for (int nd = 0; nd < 4; ++nd)
      *(f32x4*)&AccX[w - 4][ln][nd * 4] = acc[nd];
  }
  __syncthreads();
  if (w < 4) {
#pragma unroll
    for (int nd = 0; nd < 4; ++nd) {
      f32x4 o = *(const f32x4*)&AccX[w][ln][nd * 4];
#pragma unroll
      for (int j = 0; j < 4; ++j)
        AP[(size_t)(b * SQL + r0 + lh * 4 + j) * DQ + h * DH + nd * 16 + l15] =
            f2bf(acc[nd][j] + o[j]);
    }
  }
}

extern "C" void kernel_launch(void* const* d_in, const int* in_sizes, int n_in,
                              void* d_out, int out_size, void* d_ws, size_t ws_size,
                              hipStream_t stream)
{
  const float* Q   = (const float*)d_in[0];
  const float* K   = (const float*)d_in[1];
  const float* V   = (const float*)d_in[2];
  const float* aff = (const float*)d_in[3];
  const int*   qb  = (const int*)d_in[4];
  const int*   kvm = (const int*)d_in[5];
  const float* Wq  = (const float*)d_in[6];
  const float* bq  = (const float*)d_in[7];
  const float* Wk  = (const float*)d_in[8];
  const float* bk  = (const float*)d_in[9];
  const float* Wv  = (const float*)d_in[10];
  const float* bv  = (const float*)d_in[11];
  const float* Wo  = (const float*)d_in[12];
  const float* bo  = (const float*)d_in[13];
  u16*   ws   = (u16*)d_ws;
  float* outF = (float*)d_out;            // f32 output (reference returns f32)
  float* wout = outF + 1048576;           // att_weights region, f32
  u16* Kb = (u16*)wout;                   // u16 scratch inside weights region (dead until k_attn)
  u16* Vb = Kb + 4194304;
  u16* VP = Vb + 4194304;

  const int want[14] = {2097152, 4194304, 4194304, 8388608, 8388608, 8192,
                        262144, 512, 262144, 512, 262144, 512, 131072, 256};
  int bad = (n_in == 14) ? -1 : 14;
  if (bad < 0)
    for (int i = 0; i < 14; ++i)
      if (in_sizes[i] != want[i]) { bad = i; break; }
  if (bad >= 0) { k_markf<<<1, 64, 0, stream>>>(outF, 1024.0f * (160.0f + (float)bad)); return; }
  if (ws_size < WS_NEED_BYTES) { k_markf<<<1, 64, 0, stream>>>(outF, 180224.0f); return; }

  k_conv_x<<<5120, 256, 0, stream>>>(Q, K, V, ws + OFF_QB, Kb, Vb);
  k_conv_w<<<448, 256, 0, stream>>>(Wq, Wk, Wv, Wo, ws + OFF_BQ, ws + OFF_BK, ws + OFF_BV, ws + OFF_BO);
  k_gemm<u16><<<dim3(32, 4), 256, 0, stream>>>(ws + OFF_QB, 512, ws + OFF_BQ, 512, bq, ws + OFF_QP, 512);
  k_gemm<u16><<<dim3(64, 4), 256, 0, stream>>>(Kb, 512, ws + OFF_BK, 512, bk, ws + OFF_KP, 512);
  k_gemm<u16><<<dim3(64, 4), 256, 0, stream>>>(Vb, 512, ws + OFF_BV, 512, bv, VP, 512);
  k_transpose<<<dim3(32, 32), 256, 0, stream>>>(VP, ws + OFF_VPT);
  k_attn<<<dim3(64, 4, 2), 512, 0, stream>>>(ws + OFF_QP, ws + OFF_KP, ws + OFF_VPT,
                                             aff, qb, kvm, wout, ws + OFF_AP);
  k_gemm<float><<<dim3(32, 2), 256, 0, stream>>>(ws + OFF_AP, 512, ws + OFF_BO, 512, bo, outF, 256);
}

// Round 10
// 390.757 us; speedup vs baseline: 1.0011x; 1.0011x over previous
//
#include <hip/hip_runtime.h>
#include <stdint.h>

typedef unsigned short u16;
typedef unsigned int   u32;
typedef __bf16 bf16x8 __attribute__((ext_vector_type(8)));
typedef float  f32x4  __attribute__((ext_vector_type(4)));
typedef u32    u32x4  __attribute__((ext_vector_type(4)));
typedef u16    u16x4  __attribute__((ext_vector_type(4)));

#define SQL  1024
#define SKV  2048
#define DQ   512
#define NH   8
#define DH   64
#define NEGC (-1e9f)
#define SCALEC 0.125f

// ---- d_ws layout (u16 elements), total 15,597,568 u16 = 31.2 MB ----
#define OFF_QB  0ull
#define OFF_QP  2097152ull
#define OFF_KP  4194304ull
#define OFF_VPT 8388608ull
#define OFF_AP  12582912ull
#define OFF_BQ  14680064ull
#define OFF_BK  14942208ull
#define OFF_BV  15204352ull
#define OFF_BO  15466496ull
#define WS_NEED_BYTES (15597568ull * 2ull)

__device__ __forceinline__ u16 f2bf(float f) {
  u32 u = __float_as_uint(f);
  u32 r = u + 0x7fffu + ((u >> 16) & 1u);   // RNE
  return (u16)(r >> 16);
}
__device__ __forceinline__ float bf2f(u16 h) {
  return __uint_as_float(((u32)h) << 16);
}
__device__ __forceinline__ bf16x8 ld16(const u16* p) {
  return __builtin_bit_cast(bf16x8, *(const u32x4*)p);
}
__device__ __forceinline__ f32x4 MFMA(bf16x8 a, bf16x8 b, f32x4 c) {
  return __builtin_amdgcn_mfma_f32_16x16x32_bf16(a, b, c, 0, 0, 0);
}
__device__ __forceinline__ void cvt8(const float* src, u16* dst, int t) {
  f32x4 a = ((const f32x4*)src)[2 * t], b = ((const f32x4*)src)[2 * t + 1];
  u32x4 o;
  o[0] = (u32)f2bf(a[0]) | ((u32)f2bf(a[1]) << 16);
  o[1] = (u32)f2bf(a[2]) | ((u32)f2bf(a[3]) << 16);
  o[2] = (u32)f2bf(b[0]) | ((u32)f2bf(b[1]) << 16);
  o[3] = (u32)f2bf(b[2]) | ((u32)f2bf(b[3]) << 16);
  *(u32x4*)(dst + 8 * t) = o;
}

// ---------------- f32 code marker ----------------
__global__ void k_markf(float* outp, float val) {
  if (threadIdx.x == 0 && blockIdx.x == 0) outp[0] = val;
}

// ---------------- f32 -> bf16 conversions ----------------
__global__ __launch_bounds__(256) void k_conv_x(
    const float* __restrict__ Q, const float* __restrict__ K, const float* __restrict__ V,
    u16* __restrict__ Qb, u16* __restrict__ Kb, u16* __restrict__ Vb)
{
  int t = blockIdx.x * 256 + threadIdx.x;
  if (t < 262144)       cvt8(Q, Qb, t);
  else if (t < 786432)  cvt8(K, Kb, t - 262144);
  else                  cvt8(V, Vb, t - 786432);
}

__global__ __launch_bounds__(256) void k_conv_w(
    const float* __restrict__ Wq, const float* __restrict__ Wk,
    const float* __restrict__ Wv, const float* __restrict__ Wo,
    u16* __restrict__ BQ, u16* __restrict__ BK, u16* __restrict__ BV, u16* __restrict__ BO)
{
  int t = blockIdx.x * 256 + threadIdx.x;
  if (t < 32768)        cvt8(Wq, BQ, t);
  else if (t < 65536)   cvt8(Wk, BK, t - 32768);
  else if (t < 98304)   cvt8(Wv, BV, t - 65536);
  else                  cvt8(Wo, BO, t - 98304);
}

// ---------------- GEMM: out[m][n] = sum_k A[m][k]*B2[n][k] + bias[n], K=512 ----------------
template <typename OUT_T>
__global__ __launch_bounds__(256) void k_gemm(
    const u16* __restrict__ A, int lda,
    const u16* __restrict__ B2, int ldb,
    const float* __restrict__ bias,
    OUT_T* __restrict__ out, int ldo)
{
  __shared__ u16 As[128 * 72], Bs[128 * 72];
  const int tid = threadIdx.x;
  const int wid = tid >> 6, ln = tid & 63;
  const int l15 = ln & 15, lh = ln >> 4;
  const int m0 = blockIdx.x * 128, n0 = blockIdx.y * 128;
  const int wm = (wid & 1) * 64, wn = (wid >> 1) * 64;

  f32x4 acc[4][4];
#pragma unroll
  for (int mi = 0; mi < 4; ++mi)
#pragma unroll
    for (int ni = 0; ni < 4; ++ni) acc[mi][ni] = (f32x4){0.f, 0.f, 0.f, 0.f};

  for (int k0 = 0; k0 < 512; k0 += 64) {
#pragma unroll
    for (int s5 = 0; s5 < 4; ++s5) {
      int ci = s5 * 256 + tid;
      int row = ci >> 3, kc = ci & 7;
      *(u32x4*)(As + row * 72 + kc * 8) =
          *(const u32x4*)(A + (size_t)(m0 + row) * lda + k0 + kc * 8);
      *(u32x4*)(Bs + row * 72 + kc * 8) =
          *(const u32x4*)(B2 + (size_t)(n0 + row) * ldb + k0 + kc * 8);
    }
    __syncthreads();
    bf16x8 af[4][2], bfr[4][2];
#pragma unroll
    for (int mi = 0; mi < 4; ++mi) {
      int r = wm + mi * 16 + l15;
#pragma unroll
      for (int ks = 0; ks < 2; ++ks)
        af[mi][ks] = ld16(As + r * 72 + (ks * 4 + lh) * 8);
    }
#pragma unroll
    for (int ni = 0; ni < 4; ++ni) {
      int r = wn + ni * 16 + l15;
#pragma unroll
      for (int ks = 0; ks < 2; ++ks)
        bfr[ni][ks] = ld16(Bs + r * 72 + (ks * 4 + lh) * 8);
    }
#pragma unroll
    for (int mi = 0; mi < 4; ++mi)
#pragma unroll
      for (int ni = 0; ni < 4; ++ni) {
        acc[mi][ni] = MFMA(af[mi][0], bfr[ni][0], acc[mi][ni]);
        acc[mi][ni] = MFMA(af[mi][1], bfr[ni][1], acc[mi][ni]);
      }
    __syncthreads();
  }
  float bv[4];
#pragma unroll
  for (int ni = 0; ni < 4; ++ni) bv[ni] = bias[n0 + wn + ni * 16 + l15];
#pragma unroll
  for (int mi = 0; mi < 4; ++mi)
#pragma unroll
    for (int ni = 0; ni < 4; ++ni)
#pragma unroll
      for (int j = 0; j < 4; ++j) {
        float v = acc[mi][ni][j] + bv[ni];
        size_t idx = (size_t)(m0 + wm + mi * 16 + lh * 4 + j) * ldo + n0 + wn + ni * 16 + l15;
        if constexpr (sizeof(OUT_T) == 4) out[idx] = v;
        else                              out[idx] = f2bf(v);
      }
}

// ---------------- VP [8192][512] -> VpT [b][h][64][2048] ----------------
__global__ __launch_bounds__(256) void k_transpose(const u16* __restrict__ Vp, u16* __restrict__ VpT)
{
  __shared__ u16 T[64 * 72];
  const int bh = blockIdx.x, kt = blockIdx.y;
  const int b = bh >> 3, h = bh & 7;
  const int tid = threadIdx.x;
#pragma unroll
  for (int s = 0; s < 2; ++s) {
    int ci = s * 256 + tid;
    int row = ci >> 3, dc = ci & 7;
    *(u32x4*)(T + row * 72 + dc * 8) =
        *(const u32x4*)(Vp + (size_t)(b * 2048 + kt * 64 + row) * 512 + h * 64 + dc * 8);
  }
  __syncthreads();
#pragma unroll
  for (int s = 0; s < 2; ++s) {
    int ci = s * 256 + tid;
    int d = ci >> 3, kc = ci & 7;
    u32x4 v;
#pragma unroll
    for (int i = 0; i < 4; ++i) {
      u32 lo = T[(kc * 8 + 2 * i)     * 72 + d];
      u32 hi = T[(kc * 8 + 2 * i + 1) * 72 + d];
      v[i] = lo | (hi << 16);
    }
    *(u32x4*)(VpT + ((size_t)(b * 8 + h) * 64 + d) * 2048 + kt * 64 + kc * 8) = v;
  }
}

// ---------------- fused attention: S^T layout, no-max softmax, 2-step pipelined pass B ----------------
// grid (rt=64, b=4, hg=2); block 512 = 8 waves.
// wave w: head = hg*4 + (w&3), kvhalf = w>>2 -> kv [kvhalf*1024, +1024)
#define PSTR 144
__global__ __launch_bounds__(512, 4) void k_attn(
    const u16* __restrict__ Qp, const u16* __restrict__ Kp, const u16* __restrict__ VpT,
    const float* __restrict__ aff, const int* __restrict__ qbm, const int* __restrict__ kvm,
    float* __restrict__ wout, u16* __restrict__ AP)
{
  __shared__ u16 Plds[8 * 16 * PSTR];
  __shared__ float Ls[8][16];
  __shared__ float AccX[4][64][16];
  const int tid = threadIdx.x;
  const int w = tid >> 6, ln = tid & 63;
  const int l15 = ln & 15, lh = ln >> 4;
  const int b = blockIdx.y, rt = blockIdx.x, hg = blockIdx.z;
  const int h = hg * 4 + (w & 3);
  const int kvhalf = w >> 2;
  const int kv0 = kvhalf * 1024;
  const int r0 = rt * 16;
  const int bh = b * NH + h;
  u16* Pl = Plds + w * 16 * PSTR;

  bf16x8 qa0, qa1;
  {
    const u16* qp = Qp + (size_t)(b * SQL + r0 + l15) * DQ + h * DH + lh * 8;
    qa0 = ld16(qp); qa1 = ld16(qp + 32);
  }

  const int    myrow   = r0 + l15;
  const float* affRow  = aff + ((size_t)b * SQL + myrow) * SKV;
  const int*   qbRow   = qbm + ((size_t)b * SQL + myrow) * SKV;
  const int*   kvb     = kvm + (size_t)b * SKV;
  float*       woutRow = wout + ((size_t)bh * SQL + myrow) * SKV;

  // s[ni][j] = S[q-row = myrow][k-col = kb + ni*16 + lh*4 + j]
  auto compute_s = [&](int kb, f32x4* s) {
#pragma unroll
    for (int ni = 0; ni < 4; ++ni) {
      const u16* kp = Kp + (size_t)(b * SKV + kb + ni * 16 + l15) * DQ + h * DH + lh * 8;
      bf16x8 k0 = ld16(kp), k1 = ld16(kp + 32);
      f32x4 z = (f32x4){0.f, 0.f, 0.f, 0.f};
      z = MFMA(k0, qa0, z);
      z = MFMA(k1, qa1, z);
      s[ni] = z;
    }
#pragma unroll
    for (int ni = 0; ni < 4; ++ni) {
      const int c4 = kb + ni * 16 + lh * 4;
      f32x4 a  = *(const f32x4*)(affRow + c4);
      u32x4 qm = *(const u32x4*)(qbRow + c4);
      u32x4 km = *(const u32x4*)(kvb + c4);
#pragma unroll
      for (int j = 0; j < 4; ++j) {
        float v = s[ni][j] * SCALEC;
        v = km[j] ? NEGC : v;   // kv mask BEFORE aff (ref order)
        v = v * a[j];
        v = qm[j] ? NEGC : v;
        s[ni][j] = v;
      }
    }
  };

  // ---- pass A: sum of exp(s); unroll 2 lets next step's loads overlap exp chain ----
  float sum = 0.f;
#pragma unroll 2
  for (int t = 0; t < 16; ++t) {
    f32x4 s[4];
    compute_s(kv0 + t * 64, s);
#pragma unroll
    for (int ni = 0; ni < 4; ++ni)
#pragma unroll
      for (int j = 0; j < 4; ++j) sum += __expf(s[ni][j]);
  }
  sum += __shfl_xor(sum, 16);
  sum += __shfl_xor(sum, 32);
  if (ln < 16) Ls[w][ln] = sum;
  __syncthreads();
  const float rl = 1.0f / (sum + Ls[w ^ 4][l15]);

  f32x4 acc[4];
#pragma unroll
  for (int nd = 0; nd < 4; ++nd) acc[nd] = (f32x4){0.f, 0.f, 0.f, 0.f};

  // ---- pass B: 2 kv-steps per lgkm wall ----
  for (int tt = 0; tt < 8; ++tt) {
    const int kb0 = kv0 + tt * 128;
    const int kb1 = kb0 + 64;
    f32x4 s0[4], s1[4];
    compute_s(kb0, s0);
    compute_s(kb1, s1);
#pragma unroll
    for (int ni = 0; ni < 4; ++ni) {
      f32x4 wv; u16x4 pb;
#pragma unroll
      for (int j = 0; j < 4; ++j) { wv[j] = __expf(s0[ni][j]) * rl; pb[j] = f2bf(wv[j]); }
      *(f32x4*)(woutRow + kb0 + ni * 16 + lh * 4) = wv;
      *(u16x4*)(Pl + l15 * PSTR + ni * 16 + lh * 4) = pb;
    }
#pragma unroll
    for (int ni = 0; ni < 4; ++ni) {
      f32x4 wv; u16x4 pb;
#pragma unroll
      for (int j = 0; j < 4; ++j) { wv[j] = __expf(s1[ni][j]) * rl; pb[j] = f2bf(wv[j]); }
      *(f32x4*)(woutRow + kb1 + ni * 16 + lh * 4) = wv;
      *(u16x4*)(Pl + l15 * PSTR + 64 + ni * 16 + lh * 4) = pb;
    }
    // issue step-0 V loads BEFORE the wall: in flight during the lgkm wait
    bf16x8 va[4], vb[4];
#pragma unroll
    for (int nd = 0; nd < 4; ++nd) {
      const u16* vp = VpT + (size_t)(bh * DH + nd * 16 + l15) * SKV + kb0 + lh * 8;
      va[nd] = ld16(vp);
      vb[nd] = ld16(vp + 32);
    }
    asm volatile("s_waitcnt lgkmcnt(0)" ::: "memory");
    __builtin_amdgcn_sched_barrier(0);
    bf16x8 pa0 = ld16(Pl + l15 * PSTR + lh * 8);
    bf16x8 pa1 = ld16(Pl + l15 * PSTR + 32 + lh * 8);
    bf16x8 pb0 = ld16(Pl + l15 * PSTR + 64 + lh * 8);
    bf16x8 pb1 = ld16(Pl + l15 * PSTR + 96 + lh * 8);
#pragma unroll
    for (int nd = 0; nd < 4; ++nd) {
      acc[nd] = MFMA(pa0, va[nd], acc[nd]);
      acc[nd] = MFMA(pa1, vb[nd], acc[nd]);
    }
    // step-1 V loads issue here, overlap step-0 PV MFMAs
#pragma unroll
    for (int nd = 0; nd < 4; ++nd) {
      const u16* vp = VpT + (size_t)(bh * DH + nd * 16 + l15) * SKV + kb1 + lh * 8;
      bf16x8 v0 = ld16(vp);
      bf16x8 v1 = ld16(vp + 32);
      acc[nd] = MFMA(pb0, v0, acc[nd]);
      acc[nd] = MFMA(pb1, v1, acc[nd]);
    }
  }

  // ---- combine partial PV across kv-halves, write AP ----
  if (w >= 4) {
#pragma unroll
    for (int nd = 0; nd < 4; ++nd)
      *(f32x4*)&AccX[w - 4][ln][nd * 4] = acc[nd];
  }
  __syncthreads();
  if (w < 4) {
#pragma unroll
    for (int nd = 0; nd < 4; ++nd) {
      f32x4 o = *(const f32x4*)&AccX[w][ln][nd * 4];
#pragma unroll
      for (int j = 0; j < 4; ++j)
        AP[(size_t)(b * SQL + r0 + lh * 4 + j) * DQ + h * DH + nd * 16 + l15] =
            f2bf(acc[nd][j] + o[j]);
    }
  }
}

extern "C" void kernel_launch(void* const* d_in, const int* in_sizes, int n_in,
                              void* d_out, int out_size, void* d_ws, size_t ws_size,
                              hipStream_t stream)
{
  const float* Q   = (const float*)d_in[0];
  const float* K   = (const float*)d_in[1];
  const float* V   = (const float*)d_in[2];
  const float* aff = (const float*)d_in[3];
  const int*   qb  = (const int*)d_in[4];
  const int*   kvm = (const int*)d_in[5];
  const float* Wq  = (const float*)d_in[6];
  const float* bq  = (const float*)d_in[7];
  const float* Wk  = (const float*)d_in[8];
  const float* bk  = (const float*)d_in[9];
  const float* Wv  = (const float*)d_in[10];
  const float* bv  = (const float*)d_in[11];
  const float* Wo  = (const float*)d_in[12];
  const float* bo  = (const float*)d_in[13];
  u16*   ws   = (u16*)d_ws;
  float* outF = (float*)d_out;            // f32 output (reference returns f32)
  float* wout = outF + 1048576;           // att_weights region, f32
  u16* Kb = (u16*)wout;                   // u16 scratch inside weights region (dead until k_attn)
  u16* Vb = Kb + 4194304;
  u16* VP = Vb + 4194304;

  const int want[14] = {2097152, 4194304, 4194304, 8388608, 8388608, 8192,
                        262144, 512, 262144, 512, 262144, 512, 131072, 256};
  int bad = (n_in == 14) ? -1 : 14;
  if (bad < 0)
    for (int i = 0; i < 14; ++i)
      if (in_sizes[i] != want[i]) { bad = i; break; }
  if (bad >= 0) { k_markf<<<1, 64, 0, stream>>>(outF, 1024.0f * (160.0f + (float)bad)); return; }
  if (ws_size < WS_NEED_BYTES) { k_markf<<<1, 64, 0, stream>>>(outF, 180224.0f); return; }

  k_conv_x<<<5120, 256, 0, stream>>>(Q, K, V, ws + OFF_QB, Kb, Vb);
  k_conv_w<<<448, 256, 0, stream>>>(Wq, Wk, Wv, Wo, ws + OFF_BQ, ws + OFF_BK, ws + OFF_BV, ws + OFF_BO);
  k_gemm<u16><<<dim3(32, 4), 256, 0, stream>>>(ws + OFF_QB, 512, ws + OFF_BQ, 512, bq, ws + OFF_QP, 512);
  k_gemm<u16><<<dim3(64, 4), 256, 0, stream>>>(Kb, 512, ws + OFF_BK, 512, bk, ws + OFF_KP, 512);
  k_gemm<u16><<<dim3(64, 4), 256, 0, stream>>>(Vb, 512, ws + OFF_BV, 512, bv, VP, 512);
  k_transpose<<<dim3(32, 32), 256, 0, stream>>>(VP, ws + OFF_VPT);
  k_attn<<<dim3(64, 4, 2), 512, 0, stream>>>(ws + OFF_QP, ws + OFF_KP, ws + OFF_VPT,
                                             aff, qb, kvm, wout, ws + OFF_AP);
  k_gemm<float><<<dim3(32, 2), 256, 0, stream>>>(ws + OFF_AP, 512, ws + OFF_BO, 512, bo, outF, 256);
}

// Round 11
// 313.073 us; speedup vs baseline: 1.2495x; 1.2481x over previous
//
#include <hip/hip_runtime.h>
#include <stdint.h>

typedef unsigned short u16;
typedef unsigned int   u32;
typedef __bf16 bf16x8 __attribute__((ext_vector_type(8)));
typedef float  f32x4  __attribute__((ext_vector_type(4)));
typedef u32    u32x4  __attribute__((ext_vector_type(4)));
typedef u16    u16x4  __attribute__((ext_vector_type(4)));

#define SQL  1024
#define SKV  2048
#define DQ   512
#define NH   8
#define DH   64
#define NEGC (-1e9f)
#define SCALEC 0.125f

// ---- d_ws layout (u16 elements), total 15,597,568 u16 = 31.2 MB ----
#define OFF_QB  0ull
#define OFF_QP  2097152ull
#define OFF_KP  4194304ull
#define OFF_VPT 8388608ull
#define OFF_AP  12582912ull
#define OFF_BQ  14680064ull
#define OFF_BK  14942208ull
#define OFF_BV  15204352ull
#define OFF_BO  15466496ull
#define WS_NEED_BYTES (15597568ull * 2ull)

__device__ __forceinline__ u16 f2bf(float f) {
  u32 u = __float_as_uint(f);
  u32 r = u + 0x7fffu + ((u >> 16) & 1u);   // RNE
  return (u16)(r >> 16);
}
__device__ __forceinline__ float bf2f(u16 h) {
  return __uint_as_float(((u32)h) << 16);
}
__device__ __forceinline__ bf16x8 ld16(const u16* p) {
  return __builtin_bit_cast(bf16x8, *(const u32x4*)p);
}
__device__ __forceinline__ f32x4 MFMA(bf16x8 a, bf16x8 b, f32x4 c) {
  return __builtin_amdgcn_mfma_f32_16x16x32_bf16(a, b, c, 0, 0, 0);
}
__device__ __forceinline__ void cvt8(const float* src, u16* dst, int t) {
  f32x4 a = ((const f32x4*)src)[2 * t], b = ((const f32x4*)src)[2 * t + 1];
  u32x4 o;
  o[0] = (u32)f2bf(a[0]) | ((u32)f2bf(a[1]) << 16);
  o[1] = (u32)f2bf(a[2]) | ((u32)f2bf(a[3]) << 16);
  o[2] = (u32)f2bf(b[0]) | ((u32)f2bf(b[1]) << 16);
  o[3] = (u32)f2bf(b[2]) | ((u32)f2bf(b[3]) << 16);
  *(u32x4*)(dst + 8 * t) = o;
}
// build bf16x8 from 8 f32
__device__ __forceinline__ bf16x8 pack8(f32x4 a, f32x4 b) {
  u32x4 o;
  o[0] = (u32)f2bf(a[0]) | ((u32)f2bf(a[1]) << 16);
  o[1] = (u32)f2bf(a[2]) | ((u32)f2bf(a[3]) << 16);
  o[2] = (u32)f2bf(b[0]) | ((u32)f2bf(b[1]) << 16);
  o[3] = (u32)f2bf(b[2]) | ((u32)f2bf(b[3]) << 16);
  return __builtin_bit_cast(bf16x8, o);
}

// ---------------- f32 code marker ----------------
__global__ void k_markf(float* outp, float val) {
  if (threadIdx.x == 0 && blockIdx.x == 0) outp[0] = val;
}

// ---------------- f32 -> bf16 conversions ----------------
__global__ __launch_bounds__(256) void k_conv_x(
    const float* __restrict__ Q, const float* __restrict__ K, const float* __restrict__ V,
    u16* __restrict__ Qb, u16* __restrict__ Kb, u16* __restrict__ Vb)
{
  int t = blockIdx.x * 256 + threadIdx.x;
  if (t < 262144)       cvt8(Q, Qb, t);
  else if (t < 786432)  cvt8(K, Kb, t - 262144);
  else                  cvt8(V, Vb, t - 786432);
}

__global__ __launch_bounds__(256) void k_conv_w(
    const float* __restrict__ Wq, const float* __restrict__ Wk,
    const float* __restrict__ Wv, const float* __restrict__ Wo,
    u16* __restrict__ BQ, u16* __restrict__ BK, u16* __restrict__ BV, u16* __restrict__ BO)
{
  int t = blockIdx.x * 256 + threadIdx.x;
  if (t < 32768)        cvt8(Wq, BQ, t);
  else if (t < 65536)   cvt8(Wk, BK, t - 32768);
  else if (t < 98304)   cvt8(Wv, BV, t - 65536);
  else                  cvt8(Wo, BO, t - 98304);
}

// ---------------- GEMM: out[m][n] = sum_k A[m][k]*B2[n][k] + bias[n], K=512 ----------------
template <typename OUT_T>
__global__ __launch_bounds__(256) void k_gemm(
    const u16* __restrict__ A, int lda,
    const u16* __restrict__ B2, int ldb,
    const float* __restrict__ bias,
    OUT_T* __restrict__ out, int ldo)
{
  __shared__ u16 As[128 * 72], Bs[128 * 72];
  const int tid = threadIdx.x;
  const int wid = tid >> 6, ln = tid & 63;
  const int l15 = ln & 15, lh = ln >> 4;
  const int m0 = blockIdx.x * 128, n0 = blockIdx.y * 128;
  const int wm = (wid & 1) * 64, wn = (wid >> 1) * 64;

  f32x4 acc[4][4];
#pragma unroll
  for (int mi = 0; mi < 4; ++mi)
#pragma unroll
    for (int ni = 0; ni < 4; ++ni) acc[mi][ni] = (f32x4){0.f, 0.f, 0.f, 0.f};

  for (int k0 = 0; k0 < 512; k0 += 64) {
#pragma unroll
    for (int s5 = 0; s5 < 4; ++s5) {
      int ci = s5 * 256 + tid;
      int row = ci >> 3, kc = ci & 7;
      *(u32x4*)(As + row * 72 + kc * 8) =
          *(const u32x4*)(A + (size_t)(m0 + row) * lda + k0 + kc * 8);
      *(u32x4*)(Bs + row * 72 + kc * 8) =
          *(const u32x4*)(B2 + (size_t)(n0 + row) * ldb + k0 + kc * 8);
    }
    __syncthreads();
    bf16x8 af[4][2], bfr[4][2];
#pragma unroll
    for (int mi = 0; mi < 4; ++mi) {
      int r = wm + mi * 16 + l15;
#pragma unroll
      for (int ks = 0; ks < 2; ++ks)
        af[mi][ks] = ld16(As + r * 72 + (ks * 4 + lh) * 8);
    }
#pragma unroll
    for (int ni = 0; ni < 4; ++ni) {
      int r = wn + ni * 16 + l15;
#pragma unroll
      for (int ks = 0; ks < 2; ++ks)
        bfr[ni][ks] = ld16(Bs + r * 72 + (ks * 4 + lh) * 8);
    }
#pragma unroll
    for (int mi = 0; mi < 4; ++mi)
#pragma unroll
      for (int ni = 0; ni < 4; ++ni) {
        acc[mi][ni] = MFMA(af[mi][0], bfr[ni][0], acc[mi][ni]);
        acc[mi][ni] = MFMA(af[mi][1], bfr[ni][1], acc[mi][ni]);
      }
    __syncthreads();
  }
  float bv[4];
#pragma unroll
  for (int ni = 0; ni < 4; ++ni) bv[ni] = bias[n0 + wn + ni * 16 + l15];
#pragma unroll
  for (int mi = 0; mi < 4; ++mi)
#pragma unroll
    for (int ni = 0; ni < 4; ++ni)
#pragma unroll
      for (int j = 0; j < 4; ++j) {
        float v = acc[mi][ni][j] + bv[ni];
        size_t idx = (size_t)(m0 + wm + mi * 16 + lh * 4 + j) * ldo + n0 + wn + ni * 16 + l15;
        if constexpr (sizeof(OUT_T) == 4) out[idx] = v;
        else                              out[idx] = f2bf(v);
      }
}

// ---------------- VP [8192][512] -> VpT [b][h][64][2048] ----------------
__global__ __launch_bounds__(256) void k_transpose(const u16* __restrict__ Vp, u16* __restrict__ VpT)
{
  __shared__ u16 T[64 * 72];
  const int bh = blockIdx.x, kt = blockIdx.y;
  const int b = bh >> 3, h = bh & 7;
  const int tid = threadIdx.x;
#pragma unroll
  for (int s = 0; s < 2; ++s) {
    int ci = s * 256 + tid;
    int row = ci >> 3, dc = ci & 7;
    *(u32x4*)(T + row * 72 + dc * 8) =
        *(const u32x4*)(Vp + (size_t)(b * 2048 + kt * 64 + row) * 512 + h * 64 + dc * 8);
  }
  __syncthreads();
#pragma unroll
  for (int s = 0; s < 2; ++s) {
    int ci = s * 256 + tid;
    int d = ci >> 3, kc = ci & 7;
    u32x4 v;
#pragma unroll
    for (int i = 0; i < 4; ++i) {
      u32 lo = T[(kc * 8 + 2 * i)     * 72 + d];
      u32 hi = T[(kc * 8 + 2 * i + 1) * 72 + d];
      v[i] = lo | (hi << 16);
    }
    *(u32x4*)(VpT + ((size_t)(b * 8 + h) * 64 + d) * 2048 + kt * 64 + kc * 8) = v;
  }
}

// ---------------- fused attention: LDS-staged masks + coalesced wout ----------------
// grid (rt=64, b=4, hg=2); block 512 = 8 waves.
// wave w: head = hg*4 + (w&3), kvhalf = w>>2 -> kv [kvhalf*1024, +1024)
// masks for the 16 q-rows are shared by the 4 waves of each kvhalf -> staged in LDS.
#define TSTR 72
__global__ __launch_bounds__(512, 4) void k_attn(
    const u16* __restrict__ Qp, const u16* __restrict__ Kp, const u16* __restrict__ VpT,
    const float* __restrict__ aff, const int* __restrict__ qbm, const int* __restrict__ kvm,
    float* __restrict__ wout, u16* __restrict__ AP)
{
  __shared__ float AffT[2][16][TSTR];
  __shared__ u32   QmT [2][16][TSTR];
  __shared__ float Pf  [8][16][TSTR];
  __shared__ float Ls[8][16];
  const int tid = threadIdx.x;
  const int w = tid >> 6, ln = tid & 63;
  const int l15 = ln & 15, lh = ln >> 4;
  const int b = blockIdx.y, rt = blockIdx.x, hg = blockIdx.z;
  const int h = hg * 4 + (w & 3);
  const int kvhalf = w >> 2;
  const int kv0 = kvhalf * 1024;
  const int r0 = rt * 16;
  const int bh = b * NH + h;

  // staging mapping: 256B-contiguous runs per row
  const int sHalf = tid >> 8;
  const int sRow  = (tid >> 4) & 15;
  const int sCol  = (tid & 15) * 4;
  const float* affS = aff + ((size_t)b * SQL + r0 + sRow) * SKV + sHalf * 1024 + sCol;
  const int*   qbS  = qbm + ((size_t)b * SQL + r0 + sRow) * SKV + sHalf * 1024 + sCol;

  bf16x8 qa0, qa1;
  {
    const u16* qp = Qp + (size_t)(b * SQL + r0 + l15) * DQ + h * DH + lh * 8;
    qa0 = ld16(qp); qa1 = ld16(qp + 32);
  }

  const int* kvb = kvm + (size_t)b * SKV;

  auto stage = [&](int t) {
    *(f32x4*)&AffT[sHalf][sRow][sCol] = *(const f32x4*)(affS + t * 64);
    *(u32x4*)&QmT [sHalf][sRow][sCol] = *(const u32x4*)(qbS  + t * 64);
  };

  // s[ni][j] = S[q-row = r0+l15][k-col = kv0 + t*64 + ni*16 + lh*4 + j]
  auto compute_s = [&](int t, f32x4* s) {
    const int kb = kv0 + t * 64;
#pragma unroll
    for (int ni = 0; ni < 4; ++ni) {
      const u16* kp = Kp + (size_t)(b * SKV + kb + ni * 16 + l15) * DQ + h * DH + lh * 8;
      bf16x8 k0 = ld16(kp), k1 = ld16(kp + 32);
      f32x4 z = (f32x4){0.f, 0.f, 0.f, 0.f};
      z = MFMA(k0, qa0, z);
      z = MFMA(k1, qa1, z);
      s[ni] = z;
    }
#pragma unroll
    for (int ni = 0; ni < 4; ++ni) {
      const int c = ni * 16 + lh * 4;
      f32x4 a  = *(const f32x4*)&AffT[kvhalf][l15][c];
      u32x4 qm = *(const u32x4*)&QmT [kvhalf][l15][c];
      u32x4 km = *(const u32x4*)(kvb + kb + c);
#pragma unroll
      for (int j = 0; j < 4; ++j) {
        float v = s[ni][j] * SCALEC;
        v = km[j] ? NEGC : v;   // kv mask BEFORE aff (ref order)
        v = v * a[j];
        v = qm[j] ? NEGC : v;
        s[ni][j] = v;
      }
    }
  };

  // ---- pass A: sum of exp(s) ----
  float sum = 0.f;
  for (int t = 0; t < 16; ++t) {
    stage(t);
    __syncthreads();
    f32x4 s[4];
    compute_s(t, s);
#pragma unroll
    for (int ni = 0; ni < 4; ++ni)
#pragma unroll
      for (int j = 0; j < 4; ++j) sum += __expf(s[ni][j]);
    __syncthreads();
  }
  sum += __shfl_xor(sum, 16);
  sum += __shfl_xor(sum, 32);
  if (ln < 16) Ls[w][ln] = sum;
  __syncthreads();
  const float rl = 1.0f / (sum + Ls[w ^ 4][l15]);

  f32x4 acc[4];
#pragma unroll
  for (int nd = 0; nd < 4; ++nd) acc[nd] = (f32x4){0.f, 0.f, 0.f, 0.f};

  // ---- pass B ----
  for (int t = 0; t < 16; ++t) {
    const int kb = kv0 + t * 64;
    stage(t);
    __syncthreads();
    f32x4 s[4];
    compute_s(t, s);
#pragma unroll
    for (int ni = 0; ni < 4; ++ni) {
      f32x4 wv;
#pragma unroll
      for (int j = 0; j < 4; ++j) wv[j] = __expf(s[ni][j]) * rl;
      *(f32x4*)&Pf[w][l15][ni * 16 + lh * 4] = wv;
    }
    // V loads issued BEFORE the lgkm wall -> in flight during the wait
    bf16x8 va[4], vb[4];
#pragma unroll
    for (int nd = 0; nd < 4; ++nd) {
      const u16* vp = VpT + (size_t)(bh * DH + nd * 16 + l15) * SKV + kb + lh * 8;
      va[nd] = ld16(vp);
      vb[nd] = ld16(vp + 32);
    }
    asm volatile("s_waitcnt lgkmcnt(0)" ::: "memory");
    __builtin_amdgcn_sched_barrier(0);
    // P fragments from f32 tile -> bf16
    f32x4 p00 = *(const f32x4*)&Pf[w][l15][lh * 8];
    f32x4 p01 = *(const f32x4*)&Pf[w][l15][lh * 8 + 4];
    f32x4 p10 = *(const f32x4*)&Pf[w][l15][32 + lh * 8];
    f32x4 p11 = *(const f32x4*)&Pf[w][l15][32 + lh * 8 + 4];
    bf16x8 pa0 = pack8(p00, p01);
    bf16x8 pa1 = pack8(p10, p11);
#pragma unroll
    for (int nd = 0; nd < 4; ++nd) {
      acc[nd] = MFMA(pa0, va[nd], acc[nd]);
      acc[nd] = MFMA(pa1, vb[nd], acc[nd]);
    }
    // coalesced wout stores: 256B runs (4 rows x 16 lanes x 16B per instr)
#pragma unroll
    for (int i = 0; i < 4; ++i) {
      const int row = (ln >> 4) + i * 4;
      f32x4 v = *(const f32x4*)&Pf[w][row][(ln & 15) * 4];
      *(f32x4*)(wout + ((size_t)bh * SQL + r0 + row) * SKV + kb + (ln & 15) * 4) = v;
    }
    __syncthreads();
  }

  // ---- combine partial PV across kv-halves (reuse Pf as scratch), write AP ----
  float* AccXp = &Pf[0][0][0];
  if (w >= 4) {
#pragma unroll
    for (int nd = 0; nd < 4; ++nd)
      *(f32x4*)(AccXp + ((size_t)(w - 4) * 64 + ln) * 16 + nd * 4) = acc[nd];
  }
  __syncthreads();
  if (w < 4) {
#pragma unroll
    for (int nd = 0; nd < 4; ++nd) {
      f32x4 o = *(const f32x4*)(AccXp + ((size_t)w * 64 + ln) * 16 + nd * 4);
#pragma unroll
      for (int j = 0; j < 4; ++j)
        AP[(size_t)(b * SQL + r0 + lh * 4 + j) * DQ + h * DH + nd * 16 + l15] =
            f2bf(acc[nd][j] + o[j]);
    }
  }
}

extern "C" void kernel_launch(void* const* d_in, const int* in_sizes, int n_in,
                              void* d_out, int out_size, void* d_ws, size_t ws_size,
                              hipStream_t stream)
{
  const float* Q   = (const float*)d_in[0];
  const float* K   = (const float*)d_in[1];
  const float* V   = (const float*)d_in[2];
  const float* aff = (const float*)d_in[3];
  const int*   qb  = (const int*)d_in[4];
  const int*   kvm = (const int*)d_in[5];
  const float* Wq  = (const float*)d_in[6];
  const float* bq  = (const float*)d_in[7];
  const float* Wk  = (const float*)d_in[8];
  const float* bk  = (const float*)d_in[9];
  const float* Wv  = (const float*)d_in[10];
  const float* bv  = (const float*)d_in[11];
  const float* Wo  = (const float*)d_in[12];
  const float* bo  = (const float*)d_in[13];
  u16*   ws   = (u16*)d_ws;
  float* outF = (float*)d_out;            // f32 output (reference returns f32)
  float* wout = outF + 1048576;           // att_weights region, f32
  u16* Kb = (u16*)wout;                   // u16 scratch inside weights region (dead until k_attn)
  u16* Vb = Kb + 4194304;
  u16* VP = Vb + 4194304;

  const int want[14] = {2097152, 4194304, 4194304, 8388608, 8388608, 8192,
                        262144, 512, 262144, 512, 262144, 512, 131072, 256};
  int bad = (n_in == 14) ? -1 : 14;
  if (bad < 0)
    for (int i = 0; i < 14; ++i)
      if (in_sizes[i] != want[i]) { bad = i; break; }
  if (bad >= 0) { k_markf<<<1, 64, 0, stream>>>(outF, 1024.0f * (160.0f + (float)bad)); return; }
  if (ws_size < WS_NEED_BYTES) { k_markf<<<1, 64, 0, stream>>>(outF, 180224.0f); return; }

  k_conv_x<<<5120, 256, 0, stream>>>(Q, K, V, ws + OFF_QB, Kb, Vb);
  k_conv_w<<<448, 256, 0, stream>>>(Wq, Wk, Wv, Wo, ws + OFF_BQ, ws + OFF_BK, ws + OFF_BV, ws + OFF_BO);
  k_gemm<u16><<<dim3(32, 4), 256, 0, stream>>>(ws + OFF_QB, 512, ws + OFF_BQ, 512, bq, ws + OFF_QP, 512);
  k_gemm<u16><<<dim3(64, 4), 256, 0, stream>>>(Kb, 512, ws + OFF_BK, 512, bk, ws + OFF_KP, 512);
  k_gemm<u16><<<dim3(64, 4), 256, 0, stream>>>(Vb, 512, ws + OFF_BV, 512, bv, VP, 512);
  k_transpose<<<dim3(32, 32), 256, 0, stream>>>(VP, ws + OFF_VPT);
  k_attn<<<dim3(64, 4, 2), 512, 0, stream>>>(ws + OFF_QP, ws + OFF_KP, ws + OFF_VPT,
                                             aff, qb, kvm, wout, ws + OFF_AP);
  k_gemm<float><<<dim3(32, 2), 256, 0, stream>>>(ws + OFF_AP, 512, ws + OFF_BO, 512, bo, outF, 256);
}

// Round 12
// 270.040 us; speedup vs baseline: 1.4486x; 1.1594x over previous
//
#include <hip/hip_runtime.h>
#include <stdint.h>

typedef unsigned short u16;
typedef unsigned int   u32;
typedef __bf16 bf16x8 __attribute__((ext_vector_type(8)));
typedef float  f32x4  __attribute__((ext_vector_type(4)));
typedef u32    u32x4  __attribute__((ext_vector_type(4)));
typedef u16    u16x4  __attribute__((ext_vector_type(4)));

#define SQL  1024
#define SKV  2048
#define DQ   512
#define NH   8
#define DH   64
#define NEGC (-1e9f)
#define SCALEC 0.125f

// ---- d_ws layout (u16 elements), total 15,597,568 u16 = 31.2 MB ----
#define OFF_QB  0ull
#define OFF_QP  2097152ull
#define OFF_KP  4194304ull
#define OFF_VPT 8388608ull
#define OFF_AP  12582912ull
#define OFF_BQ  14680064ull
#define OFF_BK  14942208ull
#define OFF_BV  15204352ull
#define OFF_BO  15466496ull
#define WS_NEED_BYTES (15597568ull * 2ull)

__device__ __forceinline__ u16 f2bf(float f) {
  u32 u = __float_as_uint(f);
  u32 r = u + 0x7fffu + ((u >> 16) & 1u);   // RNE
  return (u16)(r >> 16);
}
__device__ __forceinline__ float bf2f(u16 h) {
  return __uint_as_float(((u32)h) << 16);
}
__device__ __forceinline__ bf16x8 ld16(const u16* p) {
  return __builtin_bit_cast(bf16x8, *(const u32x4*)p);
}
__device__ __forceinline__ f32x4 MFMA(bf16x8 a, bf16x8 b, f32x4 c) {
  return __builtin_amdgcn_mfma_f32_16x16x32_bf16(a, b, c, 0, 0, 0);
}
__device__ __forceinline__ void cvt8(const float* src, u16* dst, int t) {
  f32x4 a = ((const f32x4*)src)[2 * t], b = ((const f32x4*)src)[2 * t + 1];
  u32x4 o;
  o[0] = (u32)f2bf(a[0]) | ((u32)f2bf(a[1]) << 16);
  o[1] = (u32)f2bf(a[2]) | ((u32)f2bf(a[3]) << 16);
  o[2] = (u32)f2bf(b[0]) | ((u32)f2bf(b[1]) << 16);
  o[3] = (u32)f2bf(b[2]) | ((u32)f2bf(b[3]) << 16);
  *(u32x4*)(dst + 8 * t) = o;
}

// ---------------- f32 code marker ----------------
__global__ void k_markf(float* outp, float val) {
  if (threadIdx.x == 0 && blockIdx.x == 0) outp[0] = val;
}

// ---------------- f32 -> bf16 conversions ----------------
__global__ __launch_bounds__(256) void k_conv_x(
    const float* __restrict__ Q, const float* __restrict__ K, const float* __restrict__ V,
    u16* __restrict__ Qb, u16* __restrict__ Kb, u16* __restrict__ Vb)
{
  int t = blockIdx.x * 256 + threadIdx.x;
  if (t < 262144)       cvt8(Q, Qb, t);
  else if (t < 786432)  cvt8(K, Kb, t - 262144);
  else                  cvt8(V, Vb, t - 786432);
}

__global__ __launch_bounds__(256) void k_conv_w(
    const float* __restrict__ Wq, const float* __restrict__ Wk,
    const float* __restrict__ Wv, const float* __restrict__ Wo,
    u16* __restrict__ BQ, u16* __restrict__ BK, u16* __restrict__ BV, u16* __restrict__ BO)
{
  int t = blockIdx.x * 256 + threadIdx.x;
  if (t < 32768)        cvt8(Wq, BQ, t);
  else if (t < 65536)   cvt8(Wk, BK, t - 32768);
  else if (t < 98304)   cvt8(Wv, BV, t - 65536);
  else                  cvt8(Wo, BO, t - 98304);
}

// ---------------- GEMM: out[m][n] = sum_k A[m][k]*B2[n][k] + bias[n], K=512 ----------------
template <typename OUT_T>
__global__ __launch_bounds__(256) void k_gemm(
    const u16* __restrict__ A, int lda,
    const u16* __restrict__ B2, int ldb,
    const float* __restrict__ bias,
    OUT_T* __restrict__ out, int ldo)
{
  __shared__ u16 As[128 * 72], Bs[128 * 72];
  const int tid = threadIdx.x;
  const int wid = tid >> 6, ln = tid & 63;
  const int l15 = ln & 15, lh = ln >> 4;
  const int m0 = blockIdx.x * 128, n0 = blockIdx.y * 128;
  const int wm = (wid & 1) * 64, wn = (wid >> 1) * 64;

  f32x4 acc[4][4];
#pragma unroll
  for (int mi = 0; mi < 4; ++mi)
#pragma unroll
    for (int ni = 0; ni < 4; ++ni) acc[mi][ni] = (f32x4){0.f, 0.f, 0.f, 0.f};

  for (int k0 = 0; k0 < 512; k0 += 64) {
#pragma unroll
    for (int s5 = 0; s5 < 4; ++s5) {
      int ci = s5 * 256 + tid;
      int row = ci >> 3, kc = ci & 7;
      *(u32x4*)(As + row * 72 + kc * 8) =
          *(const u32x4*)(A + (size_t)(m0 + row) * lda + k0 + kc * 8);
      *(u32x4*)(Bs + row * 72 + kc * 8) =
          *(const u32x4*)(B2 + (size_t)(n0 + row) * ldb + k0 + kc * 8);
    }
    __syncthreads();
    bf16x8 af[4][2], bfr[4][2];
#pragma unroll
    for (int mi = 0; mi < 4; ++mi) {
      int r = wm + mi * 16 + l15;
#pragma unroll
      for (int ks = 0; ks < 2; ++ks)
        af[mi][ks] = ld16(As + r * 72 + (ks * 4 + lh) * 8);
    }
#pragma unroll
    for (int ni = 0; ni < 4; ++ni) {
      int r = wn + ni * 16 + l15;
#pragma unroll
      for (int ks = 0; ks < 2; ++ks)
        bfr[ni][ks] = ld16(Bs + r * 72 + (ks * 4 + lh) * 8);
    }
#pragma unroll
    for (int mi = 0; mi < 4; ++mi)
#pragma unroll
      for (int ni = 0; ni < 4; ++ni) {
        acc[mi][ni] = MFMA(af[mi][0], bfr[ni][0], acc[mi][ni]);
        acc[mi][ni] = MFMA(af[mi][1], bfr[ni][1], acc[mi][ni]);
      }
    __syncthreads();
  }
  float bv[4];
#pragma unroll
  for (int ni = 0; ni < 4; ++ni) bv[ni] = bias[n0 + wn + ni * 16 + l15];
#pragma unroll
  for (int mi = 0; mi < 4; ++mi)
#pragma unroll
    for (int ni = 0; ni < 4; ++ni)
#pragma unroll
      for (int j = 0; j < 4; ++j) {
        float v = acc[mi][ni][j] + bv[ni];
        size_t idx = (size_t)(m0 + wm + mi * 16 + lh * 4 + j) * ldo + n0 + wn + ni * 16 + l15;
        if constexpr (sizeof(OUT_T) == 4) out[idx] = v;
        else                              out[idx] = f2bf(v);
      }
}

// ---------------- VP [8192][512] -> VpT [b][h][64][2048] ----------------
__global__ __launch_bounds__(256) void k_transpose(const u16* __restrict__ Vp, u16* __restrict__ VpT)
{
  __shared__ u16 T[64 * 72];
  const int bh = blockIdx.x, kt = blockIdx.y;
  const int b = bh >> 3, h = bh & 7;
  const int tid = threadIdx.x;
#pragma unroll
  for (int s = 0; s < 2; ++s) {
    int ci = s * 256 + tid;
    int row = ci >> 3, dc = ci & 7;
    *(u32x4*)(T + row * 72 + dc * 8) =
        *(const u32x4*)(Vp + (size_t)(b * 2048 + kt * 64 + row) * 512 + h * 64 + dc * 8);
  }
  __syncthreads();
#pragma unroll
  for (int s = 0; s < 2; ++s) {
    int ci = s * 256 + tid;
    int d = ci >> 3, kc = ci & 7;
    u32x4 v;
#pragma unroll
    for (int i = 0; i < 4; ++i) {
      u32 lo = T[(kc * 8 + 2 * i)     * 72 + d];
      u32 hi = T[(kc * 8 + 2 * i + 1) * 72 + d];
      v[i] = lo | (hi << 16);
    }
    *(u32x4*)(VpT + ((size_t)(b * 8 + h) * 64 + d) * 2048 + kt * 64 + kc * 8) = v;
  }
}

// ---------------- fused attention: QBLK=32, async mask staging, fused qm, raw barriers ----------------
// grid (rt=32, b=4, hg=2); block 512 = 8 waves; 1 block/CU.
// wave w: head = hg*4 + (w&3), kvhalf = w>>2 -> kv [kvhalf*1024, +1024)
// S^T: MFMA(K, Q) -> lane: q = qg*16 + l15, k = kb + ni*16 + lh*4 + j
#define ASTR 68
#define PSTR 72
__global__ __launch_bounds__(512) void k_attn(
    const u16* __restrict__ Qp, const u16* __restrict__ Kp, const u16* __restrict__ VpT,
    const float* __restrict__ aff, const int* __restrict__ qbm, const int* __restrict__ kvm,
    float* __restrict__ wout, u16* __restrict__ AP)
{
  __shared__ float AffT[2][32][ASTR];   // fused: qm ? -1 : aff
  __shared__ u16   Pf[8][32][PSTR];     // per-wave bf16 P tile
  __shared__ float Ls[8][32];
  const int tid = threadIdx.x;
  const int w = tid >> 6, ln = tid & 63;
  const int l15 = ln & 15, lh = ln >> 4;
  const int b = blockIdx.y, rt = blockIdx.x, hg = blockIdx.z;
  const int h = hg * 4 + (w & 3);
  const int kvhalf = w >> 2;
  const int kv0 = kvhalf * 1024;
  const int r0 = rt * 32;
  const int bh = b * NH + h;

  // staging map: 512 threads cover [2 halves][32 rows][64 cols] in 256B runs
  const int sHalf = tid >> 8;
  const int sRow  = (tid >> 3) & 31;
  const int sCol  = (tid & 7) * 8;
  const float* affS = aff + ((size_t)b * SQL + r0 + sRow) * SKV + sHalf * 1024 + sCol;
  const int*   qbS  = qbm + ((size_t)b * SQL + r0 + sRow) * SKV + sHalf * 1024 + sCol;

  bf16x8 qa[2][2];
#pragma unroll
  for (int qg = 0; qg < 2; ++qg) {
    const u16* qp = Qp + (size_t)(b * SQL + r0 + qg * 16 + l15) * DQ + h * DH + lh * 8;
    qa[qg][0] = ld16(qp); qa[qg][1] = ld16(qp + 32);
  }

  const int* kvb = kvm + (size_t)b * SKV;

  f32x4 st[2];
  auto ldStage = [&](int t) {
    f32x4 a0 = *(const f32x4*)(affS + t * 64);
    f32x4 a1 = *(const f32x4*)(affS + t * 64 + 4);
    u32x4 q0 = *(const u32x4*)(qbS + t * 64);
    u32x4 q1 = *(const u32x4*)(qbS + t * 64 + 4);
#pragma unroll
    for (int j = 0; j < 4; ++j) {
      st[0][j] = q0[j] ? -1.0f : a0[j];
      st[1][j] = q1[j] ? -1.0f : a1[j];
    }
  };
  auto wrStage = [&]() {
    *(f32x4*)&AffT[sHalf][sRow][sCol]     = st[0];
    *(f32x4*)&AffT[sHalf][sRow][sCol + 4] = st[1];
  };

  // s[qg][ni][j] = masked score for q = r0+qg*16+l15, k = kb+ni*16+lh*4+j
  auto compute_s = [&](int kb, f32x4 (*s)[4]) {
#pragma unroll
    for (int ni = 0; ni < 4; ++ni) {
      const u16* kp = Kp + (size_t)(b * SKV + kb + ni * 16 + l15) * DQ + h * DH + lh * 8;
      bf16x8 k0 = ld16(kp), k1 = ld16(kp + 32);
#pragma unroll
      for (int qg = 0; qg < 2; ++qg) {
        f32x4 z = (f32x4){0.f, 0.f, 0.f, 0.f};
        z = MFMA(k0, qa[qg][0], z);
        z = MFMA(k1, qa[qg][1], z);
        s[qg][ni] = z;
      }
      u32x4 km = *(const u32x4*)(kvb + kb + ni * 16 + lh * 4);
#pragma unroll
      for (int qg = 0; qg < 2; ++qg) {
        f32x4 f = *(const f32x4*)&AffT[kvhalf][qg * 16 + l15][ni * 16 + lh * 4];
#pragma unroll
        for (int j = 0; j < 4; ++j) {
          float v = s[qg][ni][j] * SCALEC;
          v = km[j] ? NEGC : v;          // kv mask BEFORE aff (ref order)
          v = (f[j] < 0.f) ? NEGC : v * f[j];   // fused qm (sign) + aff mul
          s[qg][ni][j] = v;
        }
      }
    }
  };

  // ---- pass A: sum of exp(s) ----
  float sum[2] = {0.f, 0.f};
  ldStage(0);
  for (int t = 0; t < 16; ++t) {
    wrStage();
    ldStage((t + 1) & 15);                         // prefetch next (wraps; wrap feeds pass B)
    asm volatile("s_waitcnt lgkmcnt(0)" ::: "memory");
    __builtin_amdgcn_s_barrier();
    __builtin_amdgcn_sched_barrier(0);
    f32x4 s[2][4];
    compute_s(kv0 + t * 64, s);
#pragma unroll
    for (int qg = 0; qg < 2; ++qg)
#pragma unroll
      for (int ni = 0; ni < 4; ++ni)
#pragma unroll
        for (int j = 0; j < 4; ++j) sum[qg] += __expf(s[qg][ni][j]);
    __builtin_amdgcn_s_barrier();
  }
#pragma unroll
  for (int qg = 0; qg < 2; ++qg) {
    sum[qg] += __shfl_xor(sum[qg], 16);
    sum[qg] += __shfl_xor(sum[qg], 32);
  }
  if (ln < 16) { Ls[w][ln] = sum[0]; Ls[w][16 + ln] = sum[1]; }
  __syncthreads();
  float rl[2];
  rl[0] = 1.0f / (sum[0] + Ls[w ^ 4][l15]);
  rl[1] = 1.0f / (sum[1] + Ls[w ^ 4][16 + l15]);

  f32x4 acc[2][4];
#pragma unroll
  for (int qg = 0; qg < 2; ++qg)
#pragma unroll
    for (int nd = 0; nd < 4; ++nd) acc[qg][nd] = (f32x4){0.f, 0.f, 0.f, 0.f};

  // ---- pass B (st already holds staged(0) from pass A wrap) ----
  for (int t = 0; t < 16; ++t) {
    const int kb = kv0 + t * 64;
    wrStage();
    ldStage((t + 1) & 15);
    asm volatile("s_waitcnt lgkmcnt(0)" ::: "memory");
    __builtin_amdgcn_s_barrier();
    __builtin_amdgcn_sched_barrier(0);
    f32x4 s[2][4];
    compute_s(kb, s);
    // P tile -> LDS (bf16)
#pragma unroll
    for (int qg = 0; qg < 2; ++qg)
#pragma unroll
      for (int ni = 0; ni < 4; ++ni) {
        u16x4 pb;
#pragma unroll
        for (int j = 0; j < 4; ++j) pb[j] = f2bf(__expf(s[qg][ni][j]) * rl[qg]);
        *(u16x4*)&Pf[w][qg * 16 + l15][ni * 16 + lh * 4] = pb;
      }
    // V loads issued BEFORE the lgkm wall -> fly during the wait
    bf16x8 va[4], vb2[4];
#pragma unroll
    for (int nd = 0; nd < 4; ++nd) {
      const u16* vp = VpT + (size_t)(bh * DH + nd * 16 + l15) * SKV + kb + lh * 8;
      va[nd]  = ld16(vp);
      vb2[nd] = ld16(vp + 32);
    }
    asm volatile("s_waitcnt lgkmcnt(0)" ::: "memory");
    __builtin_amdgcn_sched_barrier(0);
    bf16x8 pa[2][2];
#pragma unroll
    for (int qg = 0; qg < 2; ++qg) {
      pa[qg][0] = ld16(&Pf[w][qg * 16 + l15][lh * 8]);
      pa[qg][1] = ld16(&Pf[w][qg * 16 + l15][32 + lh * 8]);
    }
#pragma unroll
    for (int qg = 0; qg < 2; ++qg)
#pragma unroll
      for (int nd = 0; nd < 4; ++nd) {
        acc[qg][nd] = MFMA(pa[qg][0], va[nd],  acc[qg][nd]);
        acc[qg][nd] = MFMA(pa[qg][1], vb2[nd], acc[qg][nd]);
      }
    // coalesced wout stores from Pf (4 rows x 256B per instr)
#pragma unroll
    for (int i = 0; i < 8; ++i) {
      const int row = (ln >> 4) + i * 4;
      const int col = (ln & 15) * 4;
      u16x4 pv = *(const u16x4*)&Pf[w][row][col];
      f32x4 wv;
#pragma unroll
      for (int j = 0; j < 4; ++j) wv[j] = bf2f(pv[j]);
      *(f32x4*)(wout + ((size_t)bh * SQL + r0 + row) * SKV + kb + col) = wv;
    }
    __builtin_amdgcn_s_barrier();
  }

  // ---- combine partial PV across kv-halves (reuse Pf as scratch), write AP ----
  __syncthreads();
  float* AccXp = (float*)&Pf[0][0][0];
  if (w >= 4) {
#pragma unroll
    for (int qg = 0; qg < 2; ++qg)
#pragma unroll
      for (int nd = 0; nd < 4; ++nd)
        *(f32x4*)(AccXp + (size_t)((w - 4) * 64 + ln) * 32 + qg * 16 + nd * 4) = acc[qg][nd];
  }
  __syncthreads();
  if (w < 4) {
#pragma unroll
    for (int qg = 0; qg < 2; ++qg)
#pragma unroll
      for (int nd = 0; nd < 4; ++nd) {
        f32x4 o = *(const f32x4*)(AccXp + (size_t)(w * 64 + ln) * 32 + qg * 16 + nd * 4);
#pragma unroll
        for (int j = 0; j < 4; ++j)
          AP[(size_t)(b * SQL + r0 + qg * 16 + lh * 4 + j) * DQ + h * DH + nd * 16 + l15] =
              f2bf(acc[qg][nd][j] + o[j]);
      }
  }
}

extern "C" void kernel_launch(void* const* d_in, const int* in_sizes, int n_in,
                              void* d_out, int out_size, void* d_ws, size_t ws_size,
                              hipStream_t stream)
{
  const float* Q   = (const float*)d_in[0];
  const float* K   = (const float*)d_in[1];
  const float* V   = (const float*)d_in[2];
  const float* aff = (const float*)d_in[3];
  const int*   qb  = (const int*)d_in[4];
  const int*   kvm = (const int*)d_in[5];
  const float* Wq  = (const float*)d_in[6];
  const float* bq  = (const float*)d_in[7];
  const float* Wk  = (const float*)d_in[8];
  const float* bk  = (const float*)d_in[9];
  const float* Wv  = (const float*)d_in[10];
  const float* bv  = (const float*)d_in[11];
  const float* Wo  = (const float*)d_in[12];
  const float* bo  = (const float*)d_in[13];
  u16*   ws   = (u16*)d_ws;
  float* outF = (float*)d_out;            // f32 output (reference returns f32)
  float* wout = outF + 1048576;           // att_weights region, f32
  u16* Kb = (u16*)wout;                   // u16 scratch inside weights region (dead until k_attn)
  u16* Vb = Kb + 4194304;
  u16* VP = Vb + 4194304;

  const int want[14] = {2097152, 4194304, 4194304, 8388608, 8388608, 8192,
                        262144, 512, 262144, 512, 262144, 512, 131072, 256};
  int bad = (n_in == 14) ? -1 : 14;
  if (bad < 0)
    for (int i = 0; i < 14; ++i)
      if (in_sizes[i] != want[i]) { bad = i; break; }
  if (bad >= 0) { k_markf<<<1, 64, 0, stream>>>(outF, 1024.0f * (160.0f + (float)bad)); return; }
  if (ws_size < WS_NEED_BYTES) { k_markf<<<1, 64, 0, stream>>>(outF, 180224.0f); return; }

  k_conv_x<<<5120, 256, 0, stream>>>(Q, K, V, ws + OFF_QB, Kb, Vb);
  k_conv_w<<<448, 256, 0, stream>>>(Wq, Wk, Wv, Wo, ws + OFF_BQ, ws + OFF_BK, ws + OFF_BV, ws + OFF_BO);
  k_gemm<u16><<<dim3(32, 4), 256, 0, stream>>>(ws + OFF_QB, 512, ws + OFF_BQ, 512, bq, ws + OFF_QP, 512);
  k_gemm<u16><<<dim3(64, 4), 256, 0, stream>>>(Kb, 512, ws + OFF_BK, 512, bk, ws + OFF_KP, 512);
  k_gemm<u16><<<dim3(64, 4), 256, 0, stream>>>(Vb, 512, ws + OFF_BV, 512, bv, VP, 512);
  k_transpose<<<dim3(32, 32), 256, 0, stream>>>(VP, ws + OFF_VPT);
  k_attn<<<dim3(32, 4, 2), 512, 0, stream>>>(ws + OFF_QP, ws + OFF_KP, ws + OFF_VPT,
                                             aff, qb, kvm, wout, ws + OFF_AP);
  k_gemm<float><<<dim3(32, 2), 256, 0, stream>>>(ws + OFF_AP, 512, ws + OFF_BO, 512, bo, outF, 256);
}

// Round 13
// 252.730 us; speedup vs baseline: 1.5479x; 1.0685x over previous
//
#include <hip/hip_runtime.h>
#include <stdint.h>

typedef unsigned short u16;
typedef unsigned int   u32;
typedef __bf16 bf16x8 __attribute__((ext_vector_type(8)));
typedef float  f32x4  __attribute__((ext_vector_type(4)));
typedef u32    u32x4  __attribute__((ext_vector_type(4)));
typedef u16    u16x4  __attribute__((ext_vector_type(4)));

#define SQL  1024
#define SKV  2048
#define DQ   512
#define NH   8
#define DH   64
#define NEGC (-1e9f)
#define SCALEC 0.125f

// ---- d_ws layout (u16 elements), total 15,597,568 u16 = 31.2 MB ----
#define OFF_QB  0ull
#define OFF_QP  2097152ull
#define OFF_KP  4194304ull
#define OFF_VPT 8388608ull
#define OFF_AP  12582912ull
#define OFF_BQ  14680064ull
#define OFF_BK  14942208ull
#define OFF_BV  15204352ull
#define OFF_BO  15466496ull
#define WS_NEED_BYTES (15597568ull * 2ull)

__device__ __forceinline__ u16 f2bf(float f) {
  u32 u = __float_as_uint(f);
  u32 r = u + 0x7fffu + ((u >> 16) & 1u);   // RNE
  return (u16)(r >> 16);
}
__device__ __forceinline__ float bf2f(u16 h) {
  return __uint_as_float(((u32)h) << 16);
}
__device__ __forceinline__ bf16x8 ld16(const u16* p) {
  return __builtin_bit_cast(bf16x8, *(const u32x4*)p);
}
__device__ __forceinline__ f32x4 MFMA(bf16x8 a, bf16x8 b, f32x4 c) {
  return __builtin_amdgcn_mfma_f32_16x16x32_bf16(a, b, c, 0, 0, 0);
}
__device__ __forceinline__ void cvt8(const float* src, u16* dst, int t) {
  f32x4 a = ((const f32x4*)src)[2 * t], b = ((const f32x4*)src)[2 * t + 1];
  u32x4 o;
  o[0] = (u32)f2bf(a[0]) | ((u32)f2bf(a[1]) << 16);
  o[1] = (u32)f2bf(a[2]) | ((u32)f2bf(a[3]) << 16);
  o[2] = (u32)f2bf(b[0]) | ((u32)f2bf(b[1]) << 16);
  o[3] = (u32)f2bf(b[2]) | ((u32)f2bf(b[3]) << 16);
  *(u32x4*)(dst + 8 * t) = o;
}

// ---------------- f32 code marker ----------------
__global__ void k_markf(float* outp, float val) {
  if (threadIdx.x == 0 && blockIdx.x == 0) outp[0] = val;
}

// ---------------- f32 -> bf16 conversions ----------------
__global__ __launch_bounds__(256) void k_conv_x(
    const float* __restrict__ Q, const float* __restrict__ K, const float* __restrict__ V,
    u16* __restrict__ Qb, u16* __restrict__ Kb, u16* __restrict__ Vb)
{
  int t = blockIdx.x * 256 + threadIdx.x;
  if (t < 262144)       cvt8(Q, Qb, t);
  else if (t < 786432)  cvt8(K, Kb, t - 262144);
  else                  cvt8(V, Vb, t - 786432);
}

__global__ __launch_bounds__(256) void k_conv_w(
    const float* __restrict__ Wq, const float* __restrict__ Wk,
    const float* __restrict__ Wv, const float* __restrict__ Wo,
    u16* __restrict__ BQ, u16* __restrict__ BK, u16* __restrict__ BV, u16* __restrict__ BO)
{
  int t = blockIdx.x * 256 + threadIdx.x;
  if (t < 32768)        cvt8(Wq, BQ, t);
  else if (t < 65536)   cvt8(Wk, BK, t - 32768);
  else if (t < 98304)   cvt8(Wv, BV, t - 65536);
  else                  cvt8(Wo, BO, t - 98304);
}

// ---------------- GEMM: out[m][n] = sum_k A[m][k]*B2[n][k] + bias[n], K=512 ----------------
template <typename OUT_T>
__global__ __launch_bounds__(256) void k_gemm(
    const u16* __restrict__ A, int lda,
    const u16* __restrict__ B2, int ldb,
    const float* __restrict__ bias,
    OUT_T* __restrict__ out, int ldo)
{
  __shared__ u16 As[128 * 72], Bs[128 * 72];
  const int tid = threadIdx.x;
  const int wid = tid >> 6, ln = tid & 63;
  const int l15 = ln & 15, lh = ln >> 4;
  const int m0 = blockIdx.x * 128, n0 = blockIdx.y * 128;
  const int wm = (wid & 1) * 64, wn = (wid >> 1) * 64;

  f32x4 acc[4][4];
#pragma unroll
  for (int mi = 0; mi < 4; ++mi)
#pragma unroll
    for (int ni = 0; ni < 4; ++ni) acc[mi][ni] = (f32x4){0.f, 0.f, 0.f, 0.f};

  for (int k0 = 0; k0 < 512; k0 += 64) {
#pragma unroll
    for (int s5 = 0; s5 < 4; ++s5) {
      int ci = s5 * 256 + tid;
      int row = ci >> 3, kc = ci & 7;
      *(u32x4*)(As + row * 72 + kc * 8) =
          *(const u32x4*)(A + (size_t)(m0 + row) * lda + k0 + kc * 8);
      *(u32x4*)(Bs + row * 72 + kc * 8) =
          *(const u32x4*)(B2 + (size_t)(n0 + row) * ldb + k0 + kc * 8);
    }
    __syncthreads();
    bf16x8 af[4][2], bfr[4][2];
#pragma unroll
    for (int mi = 0; mi < 4; ++mi) {
      int r = wm + mi * 16 + l15;
#pragma unroll
      for (int ks = 0; ks < 2; ++ks)
        af[mi][ks] = ld16(As + r * 72 + (ks * 4 + lh) * 8);
    }
#pragma unroll
    for (int ni = 0; ni < 4; ++ni) {
      int r = wn + ni * 16 + l15;
#pragma unroll
      for (int ks = 0; ks < 2; ++ks)
        bfr[ni][ks] = ld16(Bs + r * 72 + (ks * 4 + lh) * 8);
    }
#pragma unroll
    for (int mi = 0; mi < 4; ++mi)
#pragma unroll
      for (int ni = 0; ni < 4; ++ni) {
        acc[mi][ni] = MFMA(af[mi][0], bfr[ni][0], acc[mi][ni]);
        acc[mi][ni] = MFMA(af[mi][1], bfr[ni][1], acc[mi][ni]);
      }
    __syncthreads();
  }
  float bv[4];
#pragma unroll
  for (int ni = 0; ni < 4; ++ni) bv[ni] = bias[n0 + wn + ni * 16 + l15];
#pragma unroll
  for (int mi = 0; mi < 4; ++mi)
#pragma unroll
    for (int ni = 0; ni < 4; ++ni)
#pragma unroll
      for (int j = 0; j < 4; ++j) {
        float v = acc[mi][ni][j] + bv[ni];
        size_t idx = (size_t)(m0 + wm + mi * 16 + lh * 4 + j) * ldo + n0 + wn + ni * 16 + l15;
        if constexpr (sizeof(OUT_T) == 4) out[idx] = v;
        else                              out[idx] = f2bf(v);
      }
}

// ---------------- VP [8192][512] -> VpT [b][h][64][2048] ----------------
__global__ __launch_bounds__(256) void k_transpose(const u16* __restrict__ Vp, u16* __restrict__ VpT)
{
  __shared__ u16 T[64 * 72];
  const int bh = blockIdx.x, kt = blockIdx.y;
  const int b = bh >> 3, h = bh & 7;
  const int tid = threadIdx.x;
#pragma unroll
  for (int s = 0; s < 2; ++s) {
    int ci = s * 256 + tid;
    int row = ci >> 3, dc = ci & 7;
    *(u32x4*)(T + row * 72 + dc * 8) =
        *(const u32x4*)(Vp + (size_t)(b * 2048 + kt * 64 + row) * 512 + h * 64 + dc * 8);
  }
  __syncthreads();
#pragma unroll
  for (int s = 0; s < 2; ++s) {
    int ci = s * 256 + tid;
    int d = ci >> 3, kc = ci & 7;
    u32x4 v;
#pragma unroll
    for (int i = 0; i < 4; ++i) {
      u32 lo = T[(kc * 8 + 2 * i)     * 72 + d];
      u32 hi = T[(kc * 8 + 2 * i + 1) * 72 + d];
      v[i] = lo | (hi << 16);
    }
    *(u32x4*)(VpT + ((size_t)(b * 8 + h) * 64 + d) * 2048 + kt * 64 + kc * 8) = v;
  }
}

// ---------------- fused attention: XCD-local blocks + 2-deep mask prefetch ----------------
// 1D grid 256: combo = id&7 -> XCD via dispatch %8; rt = id>>3.
// combo: b = combo&3, hg = combo>>2  => per-XCD L2 set = K+V+Q of one (b,hg) ~ 3MB.
// wave w: head = hg*4 + (w&3), kvhalf = w>>2 -> kv [kvhalf*1024, +1024)
#define ASTR 68
#define PSTR 72
__global__ __launch_bounds__(512) void k_attn(
    const u16* __restrict__ Qp, const u16* __restrict__ Kp, const u16* __restrict__ VpT,
    const float* __restrict__ aff, const int* __restrict__ qbm, const int* __restrict__ kvm,
    float* __restrict__ wout, u16* __restrict__ AP)
{
  __shared__ float AffT[2][32][ASTR];   // fused: qm ? -1 : aff
  __shared__ u16   Pf[8][32][PSTR];     // per-wave bf16 P tile
  __shared__ float Ls[8][32];
  const int tid = threadIdx.x;
  const int w = tid >> 6, ln = tid & 63;
  const int l15 = ln & 15, lh = ln >> 4;
  const int combo = blockIdx.x & 7, rt = blockIdx.x >> 3;
  const int b = combo & 3, hg = combo >> 2;
  const int h = hg * 4 + (w & 3);
  const int kvhalf = w >> 2;
  const int kv0 = kvhalf * 1024;
  const int r0 = rt * 32;
  const int bh = b * NH + h;

  // staging map: 512 threads cover [2 halves][32 rows][64 cols] in 256B runs
  const int sHalf = tid >> 8;
  const int sRow  = (tid >> 3) & 31;
  const int sCol  = (tid & 7) * 8;
  const float* affS = aff + ((size_t)b * SQL + r0 + sRow) * SKV + sHalf * 1024 + sCol;
  const int*   qbS  = qbm + ((size_t)b * SQL + r0 + sRow) * SKV + sHalf * 1024 + sCol;

  bf16x8 qa[2][2];
#pragma unroll
  for (int qg = 0; qg < 2; ++qg) {
    const u16* qp = Qp + (size_t)(b * SQL + r0 + qg * 16 + l15) * DQ + h * DH + lh * 8;
    qa[qg][0] = ld16(qp); qa[qg][1] = ld16(qp + 32);
  }

  const int* kvb = kvm + (size_t)b * SKV;

  auto ldStage = [&](f32x4* st, int t) {
    f32x4 a0 = *(const f32x4*)(affS + t * 64);
    f32x4 a1 = *(const f32x4*)(affS + t * 64 + 4);
    u32x4 q0 = *(const u32x4*)(qbS + t * 64);
    u32x4 q1 = *(const u32x4*)(qbS + t * 64 + 4);
#pragma unroll
    for (int j = 0; j < 4; ++j) {
      st[0][j] = q0[j] ? -1.0f : a0[j];
      st[1][j] = q1[j] ? -1.0f : a1[j];
    }
  };
  auto wrStage = [&](const f32x4* st) {
    *(f32x4*)&AffT[sHalf][sRow][sCol]     = st[0];
    *(f32x4*)&AffT[sHalf][sRow][sCol + 4] = st[1];
  };

  // s[qg][ni][j] = masked score for q = r0+qg*16+l15, k = kb+ni*16+lh*4+j
  auto compute_s = [&](int kb, f32x4 (*s)[4]) {
#pragma unroll
    for (int ni = 0; ni < 4; ++ni) {
      const u16* kp = Kp + (size_t)(b * SKV + kb + ni * 16 + l15) * DQ + h * DH + lh * 8;
      bf16x8 k0 = ld16(kp), k1 = ld16(kp + 32);
#pragma unroll
      for (int qg = 0; qg < 2; ++qg) {
        f32x4 z = (f32x4){0.f, 0.f, 0.f, 0.f};
        z = MFMA(k0, qa[qg][0], z);
        z = MFMA(k1, qa[qg][1], z);
        s[qg][ni] = z;
      }
      u32x4 km = *(const u32x4*)(kvb + kb + ni * 16 + lh * 4);
#pragma unroll
      for (int qg = 0; qg < 2; ++qg) {
        f32x4 f = *(const f32x4*)&AffT[kvhalf][qg * 16 + l15][ni * 16 + lh * 4];
#pragma unroll
        for (int j = 0; j < 4; ++j) {
          float v = s[qg][ni][j] * SCALEC;
          v = km[j] ? NEGC : v;                 // kv mask BEFORE aff (ref order)
          v = (f[j] < 0.f) ? NEGC : v * f[j];   // fused qm (sign) + aff mul
          s[qg][ni][j] = v;
        }
      }
    }
  };

  float sum[2] = {0.f, 0.f};
  auto stepA = [&](int t, f32x4* st, int tld) {
    wrStage(st);
    ldStage(st, tld);
    asm volatile("s_waitcnt lgkmcnt(0)" ::: "memory");
    __builtin_amdgcn_s_barrier();
    __builtin_amdgcn_sched_barrier(0);
    f32x4 s[2][4];
    compute_s(kv0 + t * 64, s);
#pragma unroll
    for (int qg = 0; qg < 2; ++qg)
#pragma unroll
      for (int ni = 0; ni < 4; ++ni)
#pragma unroll
        for (int j = 0; j < 4; ++j) sum[qg] += __expf(s[qg][ni][j]);
    __builtin_amdgcn_s_barrier();
  };

  // ---- pass A: sum of exp(s); 2-deep mask prefetch ----
  f32x4 sA[2], sB[2];
  ldStage(sA, 0);
  ldStage(sB, 1);
  for (int tt = 0; tt < 8; ++tt) {
    stepA(2 * tt,     sA, (2 * tt + 2) & 15);
    stepA(2 * tt + 1, sB, (2 * tt + 3) & 15);
  }
#pragma unroll
  for (int qg = 0; qg < 2; ++qg) {
    sum[qg] += __shfl_xor(sum[qg], 16);
    sum[qg] += __shfl_xor(sum[qg], 32);
  }
  if (ln < 16) { Ls[w][ln] = sum[0]; Ls[w][16 + ln] = sum[1]; }
  __syncthreads();
  float rl[2];
  rl[0] = 1.0f / (sum[0] + Ls[w ^ 4][l15]);
  rl[1] = 1.0f / (sum[1] + Ls[w ^ 4][16 + l15]);

  f32x4 acc[2][4];
#pragma unroll
  for (int qg = 0; qg < 2; ++qg)
#pragma unroll
    for (int nd = 0; nd < 4; ++nd) acc[qg][nd] = (f32x4){0.f, 0.f, 0.f, 0.f};

  auto stepB = [&](int t, f32x4* st, int tld) {
    const int kb = kv0 + t * 64;
    wrStage(st);
    ldStage(st, tld);
    asm volatile("s_waitcnt lgkmcnt(0)" ::: "memory");
    __builtin_amdgcn_s_barrier();
    __builtin_amdgcn_sched_barrier(0);
    f32x4 s[2][4];
    compute_s(kb, s);
#pragma unroll
    for (int qg = 0; qg < 2; ++qg)
#pragma unroll
      for (int ni = 0; ni < 4; ++ni) {
        u16x4 pb;
#pragma unroll
        for (int j = 0; j < 4; ++j) pb[j] = f2bf(__expf(s[qg][ni][j]) * rl[qg]);
        *(u16x4*)&Pf[w][qg * 16 + l15][ni * 16 + lh * 4] = pb;
      }
    bf16x8 va[4], vb2[4];
#pragma unroll
    for (int nd = 0; nd < 4; ++nd) {
      const u16* vp = VpT + (size_t)(bh * DH + nd * 16 + l15) * SKV + kb + lh * 8;
      va[nd]  = ld16(vp);
      vb2[nd] = ld16(vp + 32);
    }
    asm volatile("s_waitcnt lgkmcnt(0)" ::: "memory");
    __builtin_amdgcn_sched_barrier(0);
    bf16x8 pa[2][2];
#pragma unroll
    for (int qg = 0; qg < 2; ++qg) {
      pa[qg][0] = ld16(&Pf[w][qg * 16 + l15][lh * 8]);
      pa[qg][1] = ld16(&Pf[w][qg * 16 + l15][32 + lh * 8]);
    }
#pragma unroll
    for (int qg = 0; qg < 2; ++qg)
#pragma unroll
      for (int nd = 0; nd < 4; ++nd) {
        acc[qg][nd] = MFMA(pa[qg][0], va[nd],  acc[qg][nd]);
        acc[qg][nd] = MFMA(pa[qg][1], vb2[nd], acc[qg][nd]);
      }
#pragma unroll
    for (int i = 0; i < 8; ++i) {
      const int row = (ln >> 4) + i * 4;
      const int col = (ln & 15) * 4;
      u16x4 pv = *(const u16x4*)&Pf[w][row][col];
      f32x4 wv;
#pragma unroll
      for (int j = 0; j < 4; ++j) wv[j] = bf2f(pv[j]);
      *(f32x4*)(wout + ((size_t)bh * SQL + r0 + row) * SKV + kb + col) = wv;
    }
    __builtin_amdgcn_s_barrier();
  };

  // ---- pass B (sA/sB hold staged(0)/staged(1) from pass A wrap) ----
  for (int tt = 0; tt < 8; ++tt) {
    stepB(2 * tt,     sA, (2 * tt + 2) & 15);
    stepB(2 * tt + 1, sB, (2 * tt + 3) & 15);
  }

  // ---- combine partial PV across kv-halves (reuse Pf as scratch), write AP ----
  __syncthreads();
  float* AccXp = (float*)&Pf[0][0][0];
  if (w >= 4) {
#pragma unroll
    for (int qg = 0; qg < 2; ++qg)
#pragma unroll
      for (int nd = 0; nd < 4; ++nd)
        *(f32x4*)(AccXp + (size_t)((w - 4) * 64 + ln) * 32 + qg * 16 + nd * 4) = acc[qg][nd];
  }
  __syncthreads();
  if (w < 4) {
#pragma unroll
    for (int qg = 0; qg < 2; ++qg)
#pragma unroll
      for (int nd = 0; nd < 4; ++nd) {
        f32x4 o = *(const f32x4*)(AccXp + (size_t)(w * 64 + ln) * 32 + qg * 16 + nd * 4);
#pragma unroll
        for (int j = 0; j < 4; ++j)
          AP[(size_t)(b * SQL + r0 + qg * 16 + lh * 4 + j) * DQ + h * DH + nd * 16 + l15] =
              f2bf(acc[qg][nd][j] + o[j]);
      }
  }
}

extern "C" void kernel_launch(void* const* d_in, const int* in_sizes, int n_in,
                              void* d_out, int out_size, void* d_ws, size_t ws_size,
                              hipStream_t stream)
{
  const float* Q   = (const float*)d_in[0];
  const float* K   = (const float*)d_in[1];
  const float* V   = (const float*)d_in[2];
  const float* aff = (const float*)d_in[3];
  const int*   qb  = (const int*)d_in[4];
  const int*   kvm = (const int*)d_in[5];
  const float* Wq  = (const float*)d_in[6];
  const float* bq  = (const float*)d_in[7];
  const float* Wk  = (const float*)d_in[8];
  const float* bk  = (const float*)d_in[9];
  const float* Wv  = (const float*)d_in[10];
  const float* bv  = (const float*)d_in[11];
  const float* Wo  = (const float*)d_in[12];
  const float* bo  = (const float*)d_in[13];
  u16*   ws   = (u16*)d_ws;
  float* outF = (float*)d_out;            // f32 output (reference returns f32)
  float* wout = outF + 1048576;           // att_weights region, f32
  u16* Kb = (u16*)wout;                   // u16 scratch inside weights region (dead until k_attn)
  u16* Vb = Kb + 4194304;
  u16* VP = Vb + 4194304;

  const int want[14] = {2097152, 4194304, 4194304, 8388608, 8388608, 8192,
                        262144, 512, 262144, 512, 262144, 512, 131072, 256};
  int bad = (n_in == 14) ? -1 : 14;
  if (bad < 0)
    for (int i = 0; i < 14; ++i)
      if (in_sizes[i] != want[i]) { bad = i; break; }
  if (bad >= 0) { k_markf<<<1, 64, 0, stream>>>(outF, 1024.0f * (160.0f + (float)bad)); return; }
  if (ws_size < WS_NEED_BYTES) { k_markf<<<1, 64, 0, stream>>>(outF, 180224.0f); return; }

  k_conv_x<<<5120, 256, 0, stream>>>(Q, K, V, ws + OFF_QB, Kb, Vb);
  k_conv_w<<<448, 256, 0, stream>>>(Wq, Wk, Wv, Wo, ws + OFF_BQ, ws + OFF_BK, ws + OFF_BV, ws + OFF_BO);
  k_gemm<u16><<<dim3(32, 4), 256, 0, stream>>>(ws + OFF_QB, 512, ws + OFF_BQ, 512, bq, ws + OFF_QP, 512);
  k_gemm<u16><<<dim3(64, 4), 256, 0, stream>>>(Kb, 512, ws + OFF_BK, 512, bk, ws + OFF_KP, 512);
  k_gemm<u16><<<dim3(64, 4), 256, 0, stream>>>(Vb, 512, ws + OFF_BV, 512, bv, VP, 512);
  k_transpose<<<dim3(32, 32), 256, 0, stream>>>(VP, ws + OFF_VPT);
  k_attn<<<dim3(256), 512, 0, stream>>>(ws + OFF_QP, ws + OFF_KP, ws + OFF_VPT,
                                        aff, qb, kvm, wout, ws + OFF_AP);
  k_gemm<float><<<dim3(32, 2), 256, 0, stream>>>(ws + OFF_AP, 512, ws + OFF_BO, 512, bo, outF, 256);
}